// Round 4
// baseline (337.975 us; speedup 1.0000x reference)
//
#include <hip/hip_runtime.h>
#include <hip/hip_bf16.h>
#include <stdint.h>

#define B_   2
#define S_   2048
#define D_   1024
#define H_   16
#define DH_  64
#define HID_ 4096
#define M_   4096  // B_*S_

typedef __bf16 bf16x8 __attribute__((ext_vector_type(8)));
typedef float  f32x4  __attribute__((ext_vector_type(4)));

typedef const uint32_t __attribute__((address_space(1))) u32g;
typedef uint32_t       __attribute__((address_space(3))) u32l;

__device__ __forceinline__ uint16_t f2bf(float f) {
  uint32_t u = __builtin_bit_cast(uint32_t, f);
  u += 0x7FFFu + ((u >> 16) & 1u);   // RNE
  return (uint16_t)(u >> 16);
}

__device__ __forceinline__ void gload_lds16(const void* g, void* l) {
  __builtin_amdgcn_global_load_lds((u32g*)g, (u32l*)l, 16, 0, 0);
}

// swizzled LDS 16B read: row-major [*][64] bf16 tile, byte ^= (row&7)<<4
__device__ __forceinline__ const bf16x8* lds8p(const uint16_t* base, int row,
                                               int cole) {
  int byt = (cole * 2) ^ ((row & 7) << 4);
  return reinterpret_cast<const bf16x8*>(base + row * 64 + (byt >> 1));
}

// ---------- weight convert + transpose: W (K,N) f32 -> WT (N,K) bf16 ----------
__global__ void wconv_t(const float* __restrict__ W, uint16_t* __restrict__ WT,
                        int K, int N) {
  __shared__ float tile[32][33];
  int n0 = blockIdx.x * 32, k0 = blockIdx.y * 32;
  int tx = threadIdx.x, ty = threadIdx.y;  // (32,8)
#pragma unroll
  for (int i = 0; i < 4; ++i)
    tile[ty + i * 8][tx] = W[(size_t)(k0 + ty + i * 8) * N + n0 + tx];
  __syncthreads();
#pragma unroll
  for (int i = 0; i < 4; ++i)
    WT[(size_t)(n0 + ty + i * 8) * K + k0 + tx] = f2bf(tile[tx][ty + i * 8]);
}

// ---------- layernorm: f32 row (1024) -> bf16 ----------
__global__ __launch_bounds__(256) void ln_k(const float* __restrict__ x,
                                            const float* __restrict__ sc,
                                            const float* __restrict__ sh,
                                            uint16_t* __restrict__ out) {
  int row = blockIdx.x;
  int t = threadIdx.x;
  float4 v = reinterpret_cast<const float4*>(x + (size_t)row * D_)[t];
  float s = v.x + v.y + v.z + v.w;
  float ss = v.x * v.x + v.y * v.y + v.z * v.z + v.w * v.w;
#pragma unroll
  for (int off = 32; off >= 1; off >>= 1) {
    s += __shfl_xor(s, off);
    ss += __shfl_xor(ss, off);
  }
  __shared__ float red[8];
  int wid = t >> 6, lane = t & 63;
  if (lane == 0) { red[wid] = s; red[wid + 4] = ss; }
  __syncthreads();
  s = red[0] + red[1] + red[2] + red[3];
  ss = red[4] + red[5] + red[6] + red[7];
  float mean = s * (1.0f / D_);
  float var = ss * (1.0f / D_) - mean * mean;
  float rstd = rsqrtf(var + 1e-5f);
  float4 g = reinterpret_cast<const float4*>(sc)[t];
  float4 b = reinterpret_cast<const float4*>(sh)[t];
  ushort4 o;
  o.x = f2bf(g.x * (v.x - mean) * rstd + b.x);
  o.y = f2bf(g.y * (v.y - mean) * rstd + b.y);
  o.z = f2bf(g.z * (v.z - mean) * rstd + b.z);
  o.w = f2bf(g.w * (v.w - mean) * rstd + b.w);
  reinterpret_cast<ushort4*>(out + (size_t)row * D_)[t] = o;
}

// ---------- transpose V (bh,s,dh) -> VT (bh,dh,s), bf16 ----------
__global__ void vtrans_k(const uint16_t* __restrict__ V, uint16_t* __restrict__ VT) {
  __shared__ uint16_t tile[32][33];
  int s0 = blockIdx.x * 32, d0 = blockIdx.y * 32, bh = blockIdx.z;
  int tx = threadIdx.x, ty = threadIdx.y;  // (32,8)
  const uint16_t* vb = V + (size_t)bh * S_ * DH_;
  uint16_t* vtb = VT + (size_t)bh * DH_ * S_;
#pragma unroll
  for (int i = 0; i < 4; ++i)
    tile[ty + i * 8][tx] = vb[(size_t)(s0 + ty + i * 8) * DH_ + d0 + tx];
  __syncthreads();
#pragma unroll
  for (int i = 0; i < 4; ++i)
    vtb[(size_t)(d0 + ty + i * 8) * S_ + s0 + tx] = tile[tx][ty + i * 8];
}

// ---------- GEMM: A (M,K) bf16 x BT (N,K) bf16, 128x128 tile, BK=64 ----------
// 2-phase double-buffered pipeline (T3-minimum): prefetch tile t+1 while
// computing t, counted vmcnt(8) (never drain to 0 mid-loop). Critical for the
// N=1024 GEMMs whose grids give only 1 block/CU (no inter-block overlap).
// XCD-chunked block swizzle (T1) for L2 panel reuse; grids are all %8==0.
// EPI 0: qkv head-split bf16 store; 1: f32 out = resid + acc + bias; 2: gelu bf16
template <int EPI>
__global__ __launch_bounds__(256) void gemm_bt(
    const uint16_t* __restrict__ A, const uint16_t* __restrict__ BT,
    void* __restrict__ Cout, const float* __restrict__ bias,
    const float* __restrict__ resid, int M, int N, int K) {
  __shared__ uint16_t Asm_[2][128 * 64];
  __shared__ uint16_t Bsm_[2][128 * 64];
  int t = threadIdx.x;
  int lane = t & 63, wid = t >> 6;
  int wr = wid >> 1, wc = wid & 1;
  // XCD-aware bijective swizzle (nwg % 8 == 0 for all our grids)
  int nwg = gridDim.x * gridDim.y;
  int bid = blockIdx.y * gridDim.x + blockIdx.x;
  int swz = (bid & 7) * (nwg >> 3) + (bid >> 3);
  int bx = swz % gridDim.x, by = swz / gridDim.x;
  int m0 = by * 128, n0 = bx * 128;
  int l15 = lane & 15, lk8 = (lane >> 4) * 8;
  f32x4 acc[4][4] = {};

  auto STAGE = [&](int k0, int bufi) {
#pragma unroll
    for (int it = 0; it < 4; ++it) {
      int idx = it * 256 + t;
      int r = idx >> 3, c = (idx & 7) * 8;
      gload_lds16(A + (size_t)(m0 + r) * K + k0 + c, &Asm_[bufi][idx * 8]);
      gload_lds16(BT + (size_t)(n0 + r) * K + k0 + c, &Bsm_[bufi][idx * 8]);
    }
  };

  int niter = K >> 6;
  STAGE(0, 0);
  for (int ki = 0; ki < niter; ++ki) {
    int cur = ki & 1;
    if (ki + 1 < niter) {
      STAGE((ki + 1) * 64, cur ^ 1);
      asm volatile("s_waitcnt vmcnt(8)" ::: "memory");  // cur's 8 done, next's in flight
    } else {
      asm volatile("s_waitcnt vmcnt(0)" ::: "memory");
    }
    __builtin_amdgcn_s_barrier();
    asm volatile("" ::: "memory");
    __builtin_amdgcn_sched_barrier(0);
#pragma unroll
    for (int kk = 0; kk < 2; ++kk) {
      bf16x8 a[4], b[4];
#pragma unroll
      for (int mi = 0; mi < 4; ++mi)
        a[mi] = *reinterpret_cast<const bf16x8*>(
            &Asm_[cur][(wr * 64 + mi * 16 + l15) * 64 + kk * 32 + lk8]);
#pragma unroll
      for (int ni = 0; ni < 4; ++ni)
        b[ni] = *reinterpret_cast<const bf16x8*>(
            &Bsm_[cur][(wc * 64 + ni * 16 + l15) * 64 + kk * 32 + lk8]);
#pragma unroll
      for (int mi = 0; mi < 4; ++mi)
#pragma unroll
        for (int ni = 0; ni < 4; ++ni)
          acc[mi][ni] = __builtin_amdgcn_mfma_f32_16x16x32_bf16(
              a[mi], b[ni], acc[mi][ni], 0, 0, 0);
    }
    asm volatile("s_waitcnt lgkmcnt(0)" ::: "memory");  // reads of cur retired
    __builtin_amdgcn_sched_barrier(0);
    __builtin_amdgcn_s_barrier();  // before next iter's STAGE overwrites cur^1
    asm volatile("" ::: "memory");
  }
  int lr4 = (lane >> 4) * 4;
#pragma unroll
  for (int mi = 0; mi < 4; ++mi) {
#pragma unroll
    for (int ni = 0; ni < 4; ++ni) {
#pragma unroll
      for (int r = 0; r < 4; ++r) {
        int gm = m0 + wr * 64 + mi * 16 + lr4 + r;
        int gn = n0 + wc * 64 + ni * 16 + l15;
        float v = acc[mi][ni][r];
        if constexpr (EPI == 0) {
          int which = gn >> 10, nc = gn & 1023;
          int h = nc >> 6, dh = nc & 63;
          int b = gm >> 11, s = gm & 2047;
          ((uint16_t*)Cout)[((size_t)which * 32 + b * 16 + h) * (S_ * 64) +
                            (size_t)s * 64 + dh] = f2bf(v);
        } else if constexpr (EPI == 1) {
          ((float*)Cout)[(size_t)gm * N + gn] =
              resid[(size_t)gm * N + gn] + v + bias[gn];
        } else {
          float u = v + bias[gn];
          float y = 0.7978845608028654f * (u + 0.044715f * u * u * u);
          float e = __expf(2.0f * y);
          float th = 1.0f - 2.0f / (e + 1.0f);  // tanh(y), inf-safe
          ((uint16_t*)Cout)[(size_t)gm * N + gn] = f2bf(0.5f * u * (1.0f + th));
        }
      }
    }
  }
}

// ---------- flash causal attention, QBLK=64 (4 waves x 16 rows), KVBLK=64 ----------
// Block processes the q-tile PAIR (qt, 31-qt): constant 33 K-tile iters per
// block (fixes causal load imbalance). K/V double-buffered + counted-vmcnt
// prefetch; LDS tiles XOR-swizzled (zero bank conflicts, verified R2).
__global__ __launch_bounds__(256) void attn_k(const uint16_t* __restrict__ Q,
                                              const uint16_t* __restrict__ Kv,
                                              const uint16_t* __restrict__ VT,
                                              uint16_t* __restrict__ ctx) {
  __shared__ uint16_t Ksm[2][64 * 64];
  __shared__ uint16_t Vsm[2][64 * 64];  // Vt tile: [dh][key]
  __shared__ uint16_t Psm[4][16 * 64];
  int bh = blockIdx.y;
  int t = threadIdx.x, lane = t & 63, wid = t >> 6;
  int l15 = lane & 15, lk8 = (lane >> 4) * 8, lr4 = (lane >> 4) * 4;

  auto STAGE = [&](int kt, int bufi) {
    int k0 = kt * 64;
#pragma unroll
    for (int it = 0; it < 2; ++it) {
      int idx = it * 256 + t;
      int r = idx >> 3, slot = idx & 7;
      int c = (slot ^ (r & 7)) * 8;
      gload_lds16(Kv + ((size_t)bh * S_ + k0 + r) * 64 + c, &Ksm[bufi][idx * 8]);
      gload_lds16(VT + ((size_t)bh * 64 + r) * S_ + k0 + c, &Vsm[bufi][idx * 8]);
    }
  };

  for (int half = 0; half < 2; ++half) {
    int qt = half ? 31 - blockIdx.x : blockIdx.x;
    int q0 = qt * 64;
    bf16x8 qf[2];
#pragma unroll
    for (int kk = 0; kk < 2; ++kk)
      qf[kk] = *reinterpret_cast<const bf16x8*>(
          &Q[((size_t)bh * S_ + q0 + wid * 16 + l15) * 64 + kk * 32 + lk8]);
    f32x4 o[4] = {};
    float mrow[4], lsum[4];
#pragma unroll
    for (int r = 0; r < 4; ++r) { mrow[r] = -3.0e38f; lsum[r] = 0.0f; }

    int nkt = qt + 1;
    STAGE(0, 0);
    for (int kt = 0; kt < nkt; ++kt) {
      int cur = kt & 1;
      if (kt + 1 < nkt) {
        STAGE(kt + 1, cur ^ 1);
        asm volatile("s_waitcnt vmcnt(4)" ::: "memory");  // cur done, next in flight
      } else {
        asm volatile("s_waitcnt vmcnt(0)" ::: "memory");
      }
      __builtin_amdgcn_s_barrier();
      asm volatile("" ::: "memory");
      __builtin_amdgcn_sched_barrier(0);
      const uint16_t* Kb = Ksm[cur];
      const uint16_t* Vb = Vsm[cur];

      f32x4 sf[4] = {};
#pragma unroll
      for (int kk = 0; kk < 2; ++kk)
#pragma unroll
        for (int nt = 0; nt < 4; ++nt) {
          bf16x8 kb = *lds8p(Kb, nt * 16 + l15, kk * 32 + lk8);
          sf[nt] = __builtin_amdgcn_mfma_f32_16x16x32_bf16(qf[kk], kb, sf[nt], 0, 0, 0);
        }
      float sv[4][4];
      if (kt == qt) {  // only the diagonal tile needs masking (wave-uniform)
#pragma unroll
        for (int nt = 0; nt < 4; ++nt)
#pragma unroll
          for (int r = 0; r < 4; ++r) {
            float s = sf[nt][r] * 0.125f;
            int key = nt * 16 + l15;
            int qr = wid * 16 + lr4 + r;
            sv[nt][r] = (key <= qr) ? s : -3.0e38f;
          }
      } else {
#pragma unroll
        for (int nt = 0; nt < 4; ++nt)
#pragma unroll
          for (int r = 0; r < 4; ++r) sv[nt][r] = sf[nt][r] * 0.125f;
      }
      float pmax[4];
#pragma unroll
      for (int r = 0; r < 4; ++r)
        pmax[r] = fmaxf(fmaxf(sv[0][r], sv[1][r]), fmaxf(sv[2][r], sv[3][r]));
#pragma unroll
      for (int off = 8; off >= 1; off >>= 1)
#pragma unroll
        for (int r = 0; r < 4; ++r)
          pmax[r] = fmaxf(pmax[r], __shfl_xor(pmax[r], off));
      float fac[4];
#pragma unroll
      for (int r = 0; r < 4; ++r) {
        float mn = fmaxf(mrow[r], pmax[r]);
        fac[r] = __expf(mrow[r] - mn);
        mrow[r] = mn;
        lsum[r] *= fac[r];
      }
#pragma unroll
      for (int dt = 0; dt < 4; ++dt)
#pragma unroll
        for (int r = 0; r < 4; ++r) o[dt][r] *= fac[r];
      float psum[4] = {0.0f, 0.0f, 0.0f, 0.0f};
#pragma unroll
      for (int nt = 0; nt < 4; ++nt)
#pragma unroll
        for (int r = 0; r < 4; ++r) {
          float p = __expf(sv[nt][r] - mrow[r]);
          psum[r] += p;
          int prow = lr4 + r, pcol = nt * 16 + l15;
          Psm[wid][prow * 64 + ((((pcol * 2) ^ ((prow & 7) << 4))) >> 1)] = f2bf(p);
        }
#pragma unroll
      for (int off = 8; off >= 1; off >>= 1)
#pragma unroll
        for (int r = 0; r < 4; ++r) psum[r] += __shfl_xor(psum[r], off);
#pragma unroll
      for (int r = 0; r < 4; ++r) lsum[r] += psum[r];
      // PV: ctx += P (16q x 64k) @ Vt^T (64k x 64dh)
#pragma unroll
      for (int kk = 0; kk < 2; ++kk) {
        bf16x8 pa = *lds8p(Psm[wid], l15, kk * 32 + lk8);
#pragma unroll
        for (int dt = 0; dt < 4; ++dt) {
          bf16x8 vb = *lds8p(Vb, dt * 16 + l15, kk * 32 + lk8);
          o[dt] = __builtin_amdgcn_mfma_f32_16x16x32_bf16(pa, vb, o[dt], 0, 0, 0);
        }
      }
      asm volatile("s_waitcnt lgkmcnt(0)" ::: "memory");  // reads of cur done
      __builtin_amdgcn_sched_barrier(0);
      __builtin_amdgcn_s_barrier();  // before next iter overwrites buffers
      asm volatile("" ::: "memory");
    }
    int b = bh >> 4, h = bh & 15;
#pragma unroll
    for (int dt = 0; dt < 4; ++dt)
#pragma unroll
      for (int r = 0; r < 4; ++r) {
        int s = q0 + wid * 16 + lr4 + r;
        int dh = dt * 16 + l15;
        ctx[((size_t)(b * S_ + s)) * D_ + h * 64 + dh] = f2bf(o[dt][r] / lsum[r]);
      }
  }
}

extern "C" void kernel_launch(void* const* d_in, const int* in_sizes, int n_in,
                              void* d_out, int out_size, void* d_ws, size_t ws_size,
                              hipStream_t stream) {
  const float* x    = (const float*)d_in[0];
  const float* Wq   = (const float*)d_in[1];
  const float* Wk   = (const float*)d_in[2];
  const float* Wv   = (const float*)d_in[3];
  const float* Wo   = (const float*)d_in[4];
  const float* bo   = (const float*)d_in[5];
  const float* W1   = (const float*)d_in[6];
  const float* b1   = (const float*)d_in[7];
  const float* W2   = (const float*)d_in[8];
  const float* b2   = (const float*)d_in[9];
  const float* ln1s = (const float*)d_in[10];
  const float* ln1b = (const float*)d_in[11];
  const float* ln2s = (const float*)d_in[12];
  const float* ln2b = (const float*)d_in[13];
  float* out = (float*)d_out;
  char* ws = (char*)d_ws;

  const size_t MB = 1024 * 1024;
  uint16_t* WQKVT = (uint16_t*)(ws + 0);        // 6 MB  (3072 x 1024)
  uint16_t* WOT   = (uint16_t*)(ws + 6 * MB);   // 2 MB  (1024 x 1024)
  uint16_t* W1T   = (uint16_t*)(ws + 8 * MB);   // 8 MB  (4096 x 1024)
  uint16_t* W2T   = (uint16_t*)(ws + 16 * MB);  // 8 MB  (1024 x 4096)
  uint16_t* H1    = (uint16_t*)(ws + 24 * MB);  // 8 MB  (LN1 out; reused for LN2 out)
  float*    X1    = (float*)(ws + 32 * MB);     // 16 MB (attn residual, f32)
  uint16_t* QKV   = (uint16_t*)(ws + 48 * MB);  // 24 MB (q,k,v in (bh,s,dh))
  uint16_t* VTb   = (uint16_t*)(ws + 72 * MB);  // 8 MB  (v transposed (bh,dh,s))
  uint16_t* CTX   = (uint16_t*)(ws + 80 * MB);  // 8 MB
  uint16_t* FFH   = (uint16_t*)(ws + 48 * MB);  // 32 MB (reuses dead QKV/VT)

  dim3 b32x8(32, 8);
  // weight convert+transpose (bf16)
  wconv_t<<<dim3(32, 32), b32x8, 0, stream>>>(Wq, WQKVT, 1024, 1024);
  wconv_t<<<dim3(32, 32), b32x8, 0, stream>>>(Wk, WQKVT + 1024 * 1024, 1024, 1024);
  wconv_t<<<dim3(32, 32), b32x8, 0, stream>>>(Wv, WQKVT + 2 * 1024 * 1024, 1024, 1024);
  wconv_t<<<dim3(32, 32), b32x8, 0, stream>>>(Wo, WOT, 1024, 1024);
  wconv_t<<<dim3(128, 32), b32x8, 0, stream>>>(W1, W1T, 1024, 4096);
  wconv_t<<<dim3(32, 128), b32x8, 0, stream>>>(W2, W2T, 4096, 1024);

  // LN1 -> h (bf16)
  ln_k<<<M_, 256, 0, stream>>>(x, ln1s, ln1b, H1);
  // QKV projections (fused N=3072), head-split epilogue
  gemm_bt<0><<<dim3(24, 32), 256, 0, stream>>>(H1, WQKVT, QKV, nullptr, nullptr,
                                               M_, 3072, 1024);
  const uint16_t* Qp = QKV;
  const uint16_t* Kp = QKV + (size_t)32 * S_ * 64;
  const uint16_t* Vp = QKV + (size_t)64 * S_ * 64;
  vtrans_k<<<dim3(64, 2, 32), b32x8, 0, stream>>>(Vp, VTb);
  // flash causal attention (paired q-tiles: grid x = 16 pairs)
  attn_k<<<dim3(16, 32), 256, 0, stream>>>(Qp, Kp, VTb, CTX);
  // Wo projection + bias + residual -> X1 (f32)
  gemm_bt<1><<<dim3(8, 32), 256, 0, stream>>>(CTX, WOT, X1, bo, x, M_, 1024, 1024);
  // LN2 -> h2 (bf16, reuse H1)
  ln_k<<<M_, 256, 0, stream>>>(X1, ln2s, ln2b, H1);
  // FFN1 + GELU -> FFH (bf16)
  gemm_bt<2><<<dim3(32, 32), 256, 0, stream>>>(H1, W1T, FFH, b1, nullptr,
                                               M_, 4096, 1024);
  // FFN2 + bias + residual -> out (f32)
  gemm_bt<1><<<dim3(8, 32), 256, 0, stream>>>(FFH, W2T, out, b2, X1, M_, 1024, 4096);
}

// Round 5
// 321.806 us; speedup vs baseline: 1.0502x; 1.0502x over previous
//
#include <hip/hip_runtime.h>
#include <hip/hip_bf16.h>
#include <stdint.h>

#define B_   2
#define S_   2048
#define D_   1024
#define H_   16
#define DH_  64
#define HID_ 4096
#define M_   4096  // B_*S_

typedef __bf16 bf16x8 __attribute__((ext_vector_type(8)));
typedef float  f32x4  __attribute__((ext_vector_type(4)));

typedef const uint32_t __attribute__((address_space(1))) u32g;
typedef uint32_t       __attribute__((address_space(3))) u32l;

__device__ __forceinline__ uint16_t f2bf(float f) {
  uint32_t u = __builtin_bit_cast(uint32_t, f);
  u += 0x7FFFu + ((u >> 16) & 1u);   // RNE
  return (uint16_t)(u >> 16);
}

__device__ __forceinline__ void gload_lds16(const void* g, void* l) {
  __builtin_amdgcn_global_load_lds((u32g*)g, (u32l*)l, 16, 0, 0);
}

// swizzled LDS 16B read: row-major [*][64] bf16 tile, byte ^= (row&7)<<4
__device__ __forceinline__ const bf16x8* lds8p(const uint16_t* base, int row,
                                               int cole) {
  int byt = (cole * 2) ^ ((row & 7) << 4);
  return reinterpret_cast<const bf16x8*>(base + row * 64 + (byt >> 1));
}

// ---------- weight convert + transpose: W (K,N) f32 -> WT (N,K) bf16 ----------
__global__ void wconv_t(const float* __restrict__ W, uint16_t* __restrict__ WT,
                        int K, int N) {
  __shared__ float tile[32][33];
  int n0 = blockIdx.x * 32, k0 = blockIdx.y * 32;
  int tx = threadIdx.x, ty = threadIdx.y;  // (32,8)
#pragma unroll
  for (int i = 0; i < 4; ++i)
    tile[ty + i * 8][tx] = W[(size_t)(k0 + ty + i * 8) * N + n0 + tx];
  __syncthreads();
#pragma unroll
  for (int i = 0; i < 4; ++i)
    WT[(size_t)(n0 + ty + i * 8) * K + k0 + tx] = f2bf(tile[tx][ty + i * 8]);
}

// ---------- layernorm: f32 row (1024) -> bf16 ----------
__global__ __launch_bounds__(256) void ln_k(const float* __restrict__ x,
                                            const float* __restrict__ sc,
                                            const float* __restrict__ sh,
                                            uint16_t* __restrict__ out) {
  int row = blockIdx.x;
  int t = threadIdx.x;
  float4 v = reinterpret_cast<const float4*>(x + (size_t)row * D_)[t];
  float s = v.x + v.y + v.z + v.w;
  float ss = v.x * v.x + v.y * v.y + v.z * v.z + v.w * v.w;
#pragma unroll
  for (int off = 32; off >= 1; off >>= 1) {
    s += __shfl_xor(s, off);
    ss += __shfl_xor(ss, off);
  }
  __shared__ float red[8];
  int wid = t >> 6, lane = t & 63;
  if (lane == 0) { red[wid] = s; red[wid + 4] = ss; }
  __syncthreads();
  s = red[0] + red[1] + red[2] + red[3];
  ss = red[4] + red[5] + red[6] + red[7];
  float mean = s * (1.0f / D_);
  float var = ss * (1.0f / D_) - mean * mean;
  float rstd = rsqrtf(var + 1e-5f);
  float4 g = reinterpret_cast<const float4*>(sc)[t];
  float4 b = reinterpret_cast<const float4*>(sh)[t];
  ushort4 o;
  o.x = f2bf(g.x * (v.x - mean) * rstd + b.x);
  o.y = f2bf(g.y * (v.y - mean) * rstd + b.y);
  o.z = f2bf(g.z * (v.z - mean) * rstd + b.z);
  o.w = f2bf(g.w * (v.w - mean) * rstd + b.w);
  reinterpret_cast<ushort4*>(out + (size_t)row * D_)[t] = o;
}

// ---------- out = resid + bias (f32), per-row ----------
__global__ __launch_bounds__(256) void initout_k(const float* __restrict__ resid,
                                                 const float* __restrict__ bias,
                                                 float* __restrict__ out) {
  int row = blockIdx.x, t = threadIdx.x;
  float4 r = reinterpret_cast<const float4*>(resid + (size_t)row * D_)[t];
  float4 b = reinterpret_cast<const float4*>(bias)[t];
  float4 o = {r.x + b.x, r.y + b.y, r.z + b.z, r.w + b.w};
  reinterpret_cast<float4*>(out + (size_t)row * D_)[t] = o;
}

// ---------- transpose V (bh,s,dh) -> VT (bh,dh,s), bf16 ----------
__global__ void vtrans_k(const uint16_t* __restrict__ V, uint16_t* __restrict__ VT) {
  __shared__ uint16_t tile[32][33];
  int s0 = blockIdx.x * 32, d0 = blockIdx.y * 32, bh = blockIdx.z;
  int tx = threadIdx.x, ty = threadIdx.y;  // (32,8)
  const uint16_t* vb = V + (size_t)bh * S_ * DH_;
  uint16_t* vtb = VT + (size_t)bh * DH_ * S_;
#pragma unroll
  for (int i = 0; i < 4; ++i)
    tile[ty + i * 8][tx] = vb[(size_t)(s0 + ty + i * 8) * DH_ + d0 + tx];
  __syncthreads();
#pragma unroll
  for (int i = 0; i < 4; ++i)
    vtb[(size_t)(d0 + ty + i * 8) * S_ + s0 + tx] = tile[tx][ty + i * 8];
}

// ---------- GEMM: A (M,K) bf16 x BT (N,K) bf16, 128x128 tile, BK=64 ----------
// Single-buffered (32 KiB LDS -> 4-5 blocks/CU on the 768/1024-block grids;
// R4's dbuf at 64 KiB halved occupancy and was null, per m132/m233).
// LDS tiles XOR-swizzled (T2): stage with pre-swizzled global source col,
// read via lds8p -> kills the 16-way stride-128B bank conflicts (1.26e7 in R4).
// Split-K via gridDim.z (FFN2): each z-block computes a K-chunk and
// unsafeAtomicAdd's its f32 partial into a pre-initialized output.
// EPI 0: qkv head-split bf16; 1: f32 resid+acc+bias; 2: gelu bf16; 3: f32 atomicAdd
template <int EPI>
__global__ __launch_bounds__(256) void gemm_bt(
    const uint16_t* __restrict__ A, const uint16_t* __restrict__ BT,
    void* __restrict__ Cout, const float* __restrict__ bias,
    const float* __restrict__ resid, int M, int N, int K) {
  __shared__ uint16_t Asm_[128 * 64];
  __shared__ uint16_t Bsm_[128 * 64];
  int t = threadIdx.x;
  int lane = t & 63, wid = t >> 6;
  int wr = wid >> 1, wc = wid & 1;
  // XCD-aware bijective swizzle over x,y (nwg % 8 == 0 for all our grids)
  int nwg = gridDim.x * gridDim.y;
  int bid = blockIdx.y * gridDim.x + blockIdx.x;
  int swz = (bid & 7) * (nwg >> 3) + (bid >> 3);
  int bx = swz % gridDim.x, by = swz / gridDim.x;
  int m0 = by * 128, n0 = bx * 128;
  int l15 = lane & 15, lk8 = (lane >> 4) * 8;
  int ksz = K / gridDim.z;                  // split-K chunk (z=1 -> full K)
  int kbeg = blockIdx.z * ksz;
  f32x4 acc[4][4] = {};

  auto STAGE = [&](int k0) {
#pragma unroll
    for (int it = 0; it < 4; ++it) {
      int idx = it * 256 + t;
      int r = idx >> 3, slot = idx & 7;
      int c = (slot ^ (r & 7)) * 8;       // pre-swizzled source col (involution)
      gload_lds16(A + (size_t)(m0 + r) * K + k0 + c, &Asm_[idx * 8]);
      gload_lds16(BT + (size_t)(n0 + r) * K + k0 + c, &Bsm_[idx * 8]);
    }
  };

  int niter = ksz >> 6;
  for (int ki = 0; ki < niter; ++ki) {
    __syncthreads();
    STAGE(kbeg + ki * 64);
    __syncthreads();
#pragma unroll
    for (int kk = 0; kk < 2; ++kk) {
      bf16x8 a[4], b[4];
#pragma unroll
      for (int mi = 0; mi < 4; ++mi)
        a[mi] = *lds8p(Asm_, wr * 64 + mi * 16 + l15, kk * 32 + lk8);
#pragma unroll
      for (int ni = 0; ni < 4; ++ni)
        b[ni] = *lds8p(Bsm_, wc * 64 + ni * 16 + l15, kk * 32 + lk8);
#pragma unroll
      for (int mi = 0; mi < 4; ++mi)
#pragma unroll
        for (int ni = 0; ni < 4; ++ni)
          acc[mi][ni] = __builtin_amdgcn_mfma_f32_16x16x32_bf16(
              a[mi], b[ni], acc[mi][ni], 0, 0, 0);
    }
  }
  int lr4 = (lane >> 4) * 4;
#pragma unroll
  for (int mi = 0; mi < 4; ++mi) {
#pragma unroll
    for (int ni = 0; ni < 4; ++ni) {
#pragma unroll
      for (int r = 0; r < 4; ++r) {
        int gm = m0 + wr * 64 + mi * 16 + lr4 + r;
        int gn = n0 + wc * 64 + ni * 16 + l15;
        float v = acc[mi][ni][r];
        if constexpr (EPI == 0) {
          int which = gn >> 10, nc = gn & 1023;
          int h = nc >> 6, dh = nc & 63;
          int b = gm >> 11, s = gm & 2047;
          ((uint16_t*)Cout)[((size_t)which * 32 + b * 16 + h) * (S_ * 64) +
                            (size_t)s * 64 + dh] = f2bf(v);
        } else if constexpr (EPI == 1) {
          ((float*)Cout)[(size_t)gm * N + gn] =
              resid[(size_t)gm * N + gn] + v + bias[gn];
        } else if constexpr (EPI == 2) {
          float u = v + bias[gn];
          float y = 0.7978845608028654f * (u + 0.044715f * u * u * u);
          float e = __expf(2.0f * y);
          float th = 1.0f - 2.0f / (e + 1.0f);  // tanh(y), inf-safe
          ((uint16_t*)Cout)[(size_t)gm * N + gn] = f2bf(0.5f * u * (1.0f + th));
        } else {
          unsafeAtomicAdd(&((float*)Cout)[(size_t)gm * N + gn], v);
        }
      }
    }
  }
}

// ---------- flash causal attention, QBLK=64 (4 waves x 16 rows), KVBLK=64 ----------
// Block processes the q-tile PAIR (qt, 31-qt): constant 33 K-tile iters per
// block (fixes causal load imbalance). K/V double-buffered + counted-vmcnt
// prefetch; LDS tiles XOR-swizzled (zero bank conflicts, verified R2).
__global__ __launch_bounds__(256) void attn_k(const uint16_t* __restrict__ Q,
                                              const uint16_t* __restrict__ Kv,
                                              const uint16_t* __restrict__ VT,
                                              uint16_t* __restrict__ ctx) {
  __shared__ uint16_t Ksm[2][64 * 64];
  __shared__ uint16_t Vsm[2][64 * 64];  // Vt tile: [dh][key]
  __shared__ uint16_t Psm[4][16 * 64];
  int bh = blockIdx.y;
  int t = threadIdx.x, lane = t & 63, wid = t >> 6;
  int l15 = lane & 15, lk8 = (lane >> 4) * 8, lr4 = (lane >> 4) * 4;

  auto STAGE = [&](int kt, int bufi) {
    int k0 = kt * 64;
#pragma unroll
    for (int it = 0; it < 2; ++it) {
      int idx = it * 256 + t;
      int r = idx >> 3, slot = idx & 7;
      int c = (slot ^ (r & 7)) * 8;
      gload_lds16(Kv + ((size_t)bh * S_ + k0 + r) * 64 + c, &Ksm[bufi][idx * 8]);
      gload_lds16(VT + ((size_t)bh * 64 + r) * S_ + k0 + c, &Vsm[bufi][idx * 8]);
    }
  };

  for (int half = 0; half < 2; ++half) {
    int qt = half ? 31 - blockIdx.x : blockIdx.x;
    int q0 = qt * 64;
    bf16x8 qf[2];
#pragma unroll
    for (int kk = 0; kk < 2; ++kk)
      qf[kk] = *reinterpret_cast<const bf16x8*>(
          &Q[((size_t)bh * S_ + q0 + wid * 16 + l15) * 64 + kk * 32 + lk8]);
    f32x4 o[4] = {};
    float mrow[4], lsum[4];
#pragma unroll
    for (int r = 0; r < 4; ++r) { mrow[r] = -3.0e38f; lsum[r] = 0.0f; }

    int nkt = qt + 1;
    STAGE(0, 0);
    for (int kt = 0; kt < nkt; ++kt) {
      int cur = kt & 1;
      if (kt + 1 < nkt) {
        STAGE(kt + 1, cur ^ 1);
        asm volatile("s_waitcnt vmcnt(4)" ::: "memory");  // cur done, next in flight
      } else {
        asm volatile("s_waitcnt vmcnt(0)" ::: "memory");
      }
      __builtin_amdgcn_s_barrier();
      asm volatile("" ::: "memory");
      __builtin_amdgcn_sched_barrier(0);
      const uint16_t* Kb = Ksm[cur];
      const uint16_t* Vb = Vsm[cur];

      f32x4 sf[4] = {};
#pragma unroll
      for (int kk = 0; kk < 2; ++kk)
#pragma unroll
        for (int nt = 0; nt < 4; ++nt) {
          bf16x8 kb = *lds8p(Kb, nt * 16 + l15, kk * 32 + lk8);
          sf[nt] = __builtin_amdgcn_mfma_f32_16x16x32_bf16(qf[kk], kb, sf[nt], 0, 0, 0);
        }
      float sv[4][4];
      if (kt == qt) {  // only the diagonal tile needs masking (wave-uniform)
#pragma unroll
        for (int nt = 0; nt < 4; ++nt)
#pragma unroll
          for (int r = 0; r < 4; ++r) {
            float s = sf[nt][r] * 0.125f;
            int key = nt * 16 + l15;
            int qr = wid * 16 + lr4 + r;
            sv[nt][r] = (key <= qr) ? s : -3.0e38f;
          }
      } else {
#pragma unroll
        for (int nt = 0; nt < 4; ++nt)
#pragma unroll
          for (int r = 0; r < 4; ++r) sv[nt][r] = sf[nt][r] * 0.125f;
      }
      float pmax[4];
#pragma unroll
      for (int r = 0; r < 4; ++r)
        pmax[r] = fmaxf(fmaxf(sv[0][r], sv[1][r]), fmaxf(sv[2][r], sv[3][r]));
#pragma unroll
      for (int off = 8; off >= 1; off >>= 1)
#pragma unroll
        for (int r = 0; r < 4; ++r)
          pmax[r] = fmaxf(pmax[r], __shfl_xor(pmax[r], off));
      float fac[4];
#pragma unroll
      for (int r = 0; r < 4; ++r) {
        float mn = fmaxf(mrow[r], pmax[r]);
        fac[r] = __expf(mrow[r] - mn);
        mrow[r] = mn;
        lsum[r] *= fac[r];
      }
#pragma unroll
      for (int dt = 0; dt < 4; ++dt)
#pragma unroll
        for (int r = 0; r < 4; ++r) o[dt][r] *= fac[r];
      float psum[4] = {0.0f, 0.0f, 0.0f, 0.0f};
#pragma unroll
      for (int nt = 0; nt < 4; ++nt)
#pragma unroll
        for (int r = 0; r < 4; ++r) {
          float p = __expf(sv[nt][r] - mrow[r]);
          psum[r] += p;
          int prow = lr4 + r, pcol = nt * 16 + l15;
          Psm[wid][prow * 64 + ((((pcol * 2) ^ ((prow & 7) << 4))) >> 1)] = f2bf(p);
        }
#pragma unroll
      for (int off = 8; off >= 1; off >>= 1)
#pragma unroll
        for (int r = 0; r < 4; ++r) psum[r] += __shfl_xor(psum[r], off);
#pragma unroll
      for (int r = 0; r < 4; ++r) lsum[r] += psum[r];
      // PV: ctx += P (16q x 64k) @ Vt^T (64k x 64dh)
#pragma unroll
      for (int kk = 0; kk < 2; ++kk) {
        bf16x8 pa = *lds8p(Psm[wid], l15, kk * 32 + lk8);
#pragma unroll
        for (int dt = 0; dt < 4; ++dt) {
          bf16x8 vb = *lds8p(Vb, dt * 16 + l15, kk * 32 + lk8);
          o[dt] = __builtin_amdgcn_mfma_f32_16x16x32_bf16(pa, vb, o[dt], 0, 0, 0);
        }
      }
      asm volatile("s_waitcnt lgkmcnt(0)" ::: "memory");  // reads of cur done
      __builtin_amdgcn_sched_barrier(0);
      __builtin_amdgcn_s_barrier();  // before next iter overwrites buffers
      asm volatile("" ::: "memory");
    }
    int b = bh >> 4, h = bh & 15;
#pragma unroll
    for (int dt = 0; dt < 4; ++dt)
#pragma unroll
      for (int r = 0; r < 4; ++r) {
        int s = q0 + wid * 16 + lr4 + r;
        int dh = dt * 16 + l15;
        ctx[((size_t)(b * S_ + s)) * D_ + h * 64 + dh] = f2bf(o[dt][r] / lsum[r]);
      }
  }
}

extern "C" void kernel_launch(void* const* d_in, const int* in_sizes, int n_in,
                              void* d_out, int out_size, void* d_ws, size_t ws_size,
                              hipStream_t stream) {
  const float* x    = (const float*)d_in[0];
  const float* Wq   = (const float*)d_in[1];
  const float* Wk   = (const float*)d_in[2];
  const float* Wv   = (const float*)d_in[3];
  const float* Wo   = (const float*)d_in[4];
  const float* bo   = (const float*)d_in[5];
  const float* W1   = (const float*)d_in[6];
  const float* b1   = (const float*)d_in[7];
  const float* W2   = (const float*)d_in[8];
  const float* b2   = (const float*)d_in[9];
  const float* ln1s = (const float*)d_in[10];
  const float* ln1b = (const float*)d_in[11];
  const float* ln2s = (const float*)d_in[12];
  const float* ln2b = (const float*)d_in[13];
  float* out = (float*)d_out;
  char* ws = (char*)d_ws;

  const size_t MB = 1024 * 1024;
  uint16_t* WQKVT = (uint16_t*)(ws + 0);        // 6 MB  (3072 x 1024)
  uint16_t* WOT   = (uint16_t*)(ws + 6 * MB);   // 2 MB  (1024 x 1024)
  uint16_t* W1T   = (uint16_t*)(ws + 8 * MB);   // 8 MB  (4096 x 1024)
  uint16_t* W2T   = (uint16_t*)(ws + 16 * MB);  // 8 MB  (1024 x 4096)
  uint16_t* H1    = (uint16_t*)(ws + 24 * MB);  // 8 MB  (LN1 out; reused for LN2 out)
  float*    X1    = (float*)(ws + 32 * MB);     // 16 MB (attn residual, f32)
  uint16_t* QKV   = (uint16_t*)(ws + 48 * MB);  // 24 MB (q,k,v in (bh,s,dh))
  uint16_t* VTb   = (uint16_t*)(ws + 72 * MB);  // 8 MB  (v transposed (bh,dh,s))
  uint16_t* CTX   = (uint16_t*)(ws + 80 * MB);  // 8 MB
  uint16_t* FFH   = (uint16_t*)(ws + 48 * MB);  // 32 MB (reuses dead QKV/VT)

  dim3 b32x8(32, 8);
  // weight convert+transpose (bf16)
  wconv_t<<<dim3(32, 32), b32x8, 0, stream>>>(Wq, WQKVT, 1024, 1024);
  wconv_t<<<dim3(32, 32), b32x8, 0, stream>>>(Wk, WQKVT + 1024 * 1024, 1024, 1024);
  wconv_t<<<dim3(32, 32), b32x8, 0, stream>>>(Wv, WQKVT + 2 * 1024 * 1024, 1024, 1024);
  wconv_t<<<dim3(32, 32), b32x8, 0, stream>>>(Wo, WOT, 1024, 1024);
  wconv_t<<<dim3(128, 32), b32x8, 0, stream>>>(W1, W1T, 1024, 4096);
  wconv_t<<<dim3(32, 128), b32x8, 0, stream>>>(W2, W2T, 4096, 1024);

  // LN1 -> h (bf16)
  ln_k<<<M_, 256, 0, stream>>>(x, ln1s, ln1b, H1);
  // QKV projections (fused N=3072), head-split epilogue
  gemm_bt<0><<<dim3(24, 32), 256, 0, stream>>>(H1, WQKVT, QKV, nullptr, nullptr,
                                               M_, 3072, 1024);
  const uint16_t* Qp = QKV;
  const uint16_t* Kp = QKV + (size_t)32 * S_ * 64;
  const uint16_t* Vp = QKV + (size_t)64 * S_ * 64;
  vtrans_k<<<dim3(64, 2, 32), b32x8, 0, stream>>>(Vp, VTb);
  // flash causal attention (paired q-tiles: grid x = 16 pairs)
  attn_k<<<dim3(16, 32), 256, 0, stream>>>(Qp, Kp, VTb, CTX);
  // Wo projection + bias + residual -> X1 (f32); 1 block/CU swizzle probe
  gemm_bt<1><<<dim3(8, 32), 256, 0, stream>>>(CTX, WOT, X1, bo, x, M_, 1024, 1024);
  // LN2 -> h2 (bf16, reuse H1)
  ln_k<<<M_, 256, 0, stream>>>(X1, ln2s, ln2b, H1);
  // FFN1 + GELU -> FFH (bf16)
  gemm_bt<2><<<dim3(32, 32), 256, 0, stream>>>(H1, W1T, FFH, b1, nullptr,
                                               M_, 4096, 1024);
  // FFN2 split-K=4: out = X1 + b2, then 4 z-chunks atomicAdd f32 partials
  initout_k<<<M_, 256, 0, stream>>>(X1, b2, out);
  gemm_bt<3><<<dim3(8, 32, 4), 256, 0, stream>>>(FFH, W2T, out, nullptr, nullptr,
                                                 M_, 1024, 4096);
}

// Round 6
// 301.095 us; speedup vs baseline: 1.1225x; 1.0688x over previous
//
#include <hip/hip_runtime.h>
#include <hip/hip_bf16.h>
#include <stdint.h>

#define B_   2
#define S_   2048
#define D_   1024
#define H_   16
#define DH_  64
#define HID_ 4096
#define M_   4096  // B_*S_

typedef __bf16 bf16x8 __attribute__((ext_vector_type(8)));
typedef float  f32x4  __attribute__((ext_vector_type(4)));

typedef const uint32_t __attribute__((address_space(1))) u32g;
typedef uint32_t       __attribute__((address_space(3))) u32l;

__device__ __forceinline__ uint16_t f2bf(float f) {
  uint32_t u = __builtin_bit_cast(uint32_t, f);
  u += 0x7FFFu + ((u >> 16) & 1u);   // RNE
  return (uint16_t)(u >> 16);
}

__device__ __forceinline__ void gload_lds16(const void* g, void* l) {
  __builtin_amdgcn_global_load_lds((u32g*)g, (u32l*)l, 16, 0, 0);
}

// swizzled LDS 16B read: row-major [*][64] bf16 tile, byte ^= (row&7)<<4
__device__ __forceinline__ const bf16x8* lds8p(const uint16_t* base, int row,
                                               int cole) {
  int byt = (cole * 2) ^ ((row & 7) << 4);
  return reinterpret_cast<const bf16x8*>(base + row * 64 + (byt >> 1));
}

// ---------- weight convert + transpose: W (K,N) f32 -> WT (N,K) bf16 ----------
__global__ void wconv_t(const float* __restrict__ W, uint16_t* __restrict__ WT,
                        int K, int N) {
  __shared__ float tile[32][33];
  int n0 = blockIdx.x * 32, k0 = blockIdx.y * 32;
  int tx = threadIdx.x, ty = threadIdx.y;  // (32,8)
#pragma unroll
  for (int i = 0; i < 4; ++i)
    tile[ty + i * 8][tx] = W[(size_t)(k0 + ty + i * 8) * N + n0 + tx];
  __syncthreads();
#pragma unroll
  for (int i = 0; i < 4; ++i)
    WT[(size_t)(n0 + ty + i * 8) * K + k0 + tx] = f2bf(tile[tx][ty + i * 8]);
}

// ---------- layernorm: f32 row (1024) -> bf16 ----------
__global__ __launch_bounds__(256) void ln_k(const float* __restrict__ x,
                                            const float* __restrict__ sc,
                                            const float* __restrict__ sh,
                                            uint16_t* __restrict__ out) {
  int row = blockIdx.x;
  int t = threadIdx.x;
  float4 v = reinterpret_cast<const float4*>(x + (size_t)row * D_)[t];
  float s = v.x + v.y + v.z + v.w;
  float ss = v.x * v.x + v.y * v.y + v.z * v.z + v.w * v.w;
#pragma unroll
  for (int off = 32; off >= 1; off >>= 1) {
    s += __shfl_xor(s, off);
    ss += __shfl_xor(ss, off);
  }
  __shared__ float red[8];
  int wid = t >> 6, lane = t & 63;
  if (lane == 0) { red[wid] = s; red[wid + 4] = ss; }
  __syncthreads();
  s = red[0] + red[1] + red[2] + red[3];
  ss = red[4] + red[5] + red[6] + red[7];
  float mean = s * (1.0f / D_);
  float var = ss * (1.0f / D_) - mean * mean;
  float rstd = rsqrtf(var + 1e-5f);
  float4 g = reinterpret_cast<const float4*>(sc)[t];
  float4 b = reinterpret_cast<const float4*>(sh)[t];
  ushort4 o;
  o.x = f2bf(g.x * (v.x - mean) * rstd + b.x);
  o.y = f2bf(g.y * (v.y - mean) * rstd + b.y);
  o.z = f2bf(g.z * (v.z - mean) * rstd + b.z);
  o.w = f2bf(g.w * (v.w - mean) * rstd + b.w);
  reinterpret_cast<ushort4*>(out + (size_t)row * D_)[t] = o;
}

// ---------- out = resid + bias (f32), per-row ----------
__global__ __launch_bounds__(256) void initout_k(const float* __restrict__ resid,
                                                 const float* __restrict__ bias,
                                                 float* __restrict__ out) {
  int row = blockIdx.x, t = threadIdx.x;
  float4 r = reinterpret_cast<const float4*>(resid + (size_t)row * D_)[t];
  float4 b = reinterpret_cast<const float4*>(bias)[t];
  float4 o = {r.x + b.x, r.y + b.y, r.z + b.z, r.w + b.w};
  reinterpret_cast<float4*>(out + (size_t)row * D_)[t] = o;
}

// ---------- transpose V (bh,s,dh) -> VT (bh,dh,s), bf16 ----------
__global__ void vtrans_k(const uint16_t* __restrict__ V, uint16_t* __restrict__ VT) {
  __shared__ uint16_t tile[32][33];
  int s0 = blockIdx.x * 32, d0 = blockIdx.y * 32, bh = blockIdx.z;
  int tx = threadIdx.x, ty = threadIdx.y;  // (32,8)
  const uint16_t* vb = V + (size_t)bh * S_ * DH_;
  uint16_t* vtb = VT + (size_t)bh * DH_ * S_;
#pragma unroll
  for (int i = 0; i < 4; ++i)
    tile[ty + i * 8][tx] = vb[(size_t)(s0 + ty + i * 8) * DH_ + d0 + tx];
  __syncthreads();
#pragma unroll
  for (int i = 0; i < 4; ++i)
    vtb[(size_t)(d0 + ty + i * 8) * S_ + s0 + tx] = tile[tx][ty + i * 8];
}

// ================== 256x256 8-phase GEMM (T2+T3+T4+T5), BK=64 ==================
// A (M,K) bf16 x BT (N,K) bf16. 512 threads = 8 waves (2M x 4N); per-wave
// output 128x64 (8x4 16x16 frags). LDS 128 KiB: A/B x 2 dbuf x 2 M-halves of
// 128x64 bf16, XOR-swizzled via pre-swizzled global source. Schedule per
// K-tile T (4 phases, quadrants (mh,nh) = (0,0),(0,1),(1,1),(1,0)):
//   p0: ds A0+B0 | stage B0(T+1)->buf^1 | bar | lgkm0 | 16 MFMA | bar
//   p1: ds B1    | stage A1(T+1)->buf^1 | bar | lgkm0 | 16 MFMA | bar
//   p2: ds A1    | stage A0(T+2)->buf   | bar | lgkm0 | 16 MFMA | bar
//   p3: ds B0    | stage B1(T+2)->buf   | bar | lgkm0 | 16 MFMA | vmcnt(4) bar
// Overwrite safety: each region's stage is issued >=1 barrier after its last
// lgkm-drained read. vmcnt(4) = 2 half-tiles (A0,B1 of T+2) in flight; vmcnt(0)
// before the last tile. Never drains mid-loop (T4). setprio around MFMA (T5).
// EPI 0: qkv head-split bf16; 2: gelu bf16; 3: f32 unsafeAtomicAdd (split-K)
template <int EPI>
__global__ __launch_bounds__(512, 2) void gemm8(
    const uint16_t* __restrict__ A, const uint16_t* __restrict__ BT,
    void* __restrict__ Cout, const float* __restrict__ bias,
    int M, int N, int K) {
  __shared__ uint16_t As[2][2][128 * 64];
  __shared__ uint16_t Bs[2][2][128 * 64];
  int t = threadIdx.x;
  int lane = t & 63, wid = t >> 6;
  int wm = wid >> 2, wn = wid & 3;
  int l15 = lane & 15, lk8 = (lane >> 4) * 8, lr4 = (lane >> 4) * 4;
  // XCD-aware bijective swizzle over (x,y); all grids have nwg_xy % 8 == 0
  int gx = gridDim.x;
  int nwg = gx * gridDim.y;
  int bid = blockIdx.y * gx + blockIdx.x;
  int swz = (bid & 7) * (nwg >> 3) + (bid >> 3);
  int bx = swz % gx, by = swz / gx;
  int m0 = by * 256, n0 = bx * 256;
  int ksz = K / gridDim.z;
  int kbeg = blockIdx.z * ksz;
  int NT = ksz >> 6;

  // staging: half-tile 128x64 bf16 = 16 KB = 512 thr x 2 x 16 B
  int r0 = t >> 3, slot0 = t & 7;
  int scol = (slot0 ^ (r0 & 7)) * 8;  // pre-swizzled source col (involution)

  auto STAGE_A = [&](int kt, int half, int buf) {
    const uint16_t* src =
        A + (size_t)(m0 + half * 128 + r0) * K + kbeg + kt * 64 + scol;
    uint16_t* dst = &As[buf][half][t * 8];
    gload_lds16(src, dst);
    gload_lds16(src + (size_t)64 * K, dst + 4096);
  };
  auto STAGE_B = [&](int kt, int half, int buf) {
    const uint16_t* src =
        BT + (size_t)(n0 + half * 128 + r0) * K + kbeg + kt * 64 + scol;
    uint16_t* dst = &Bs[buf][half][t * 8];
    gload_lds16(src, dst);
    gload_lds16(src + (size_t)64 * K, dst + 4096);
  };

  bf16x8 a[4][2], b[2][2];
  auto LDA = [&](int buf, int mh) {
#pragma unroll
    for (int j = 0; j < 4; ++j)
#pragma unroll
      for (int kk = 0; kk < 2; ++kk)
        a[j][kk] = *lds8p(As[buf][mh], wm * 64 + j * 16 + l15, kk * 32 + lk8);
  };
  auto LDB = [&](int buf, int nh) {
#pragma unroll
    for (int jj = 0; jj < 2; ++jj)
#pragma unroll
      for (int kk = 0; kk < 2; ++kk)
        b[jj][kk] = *lds8p(Bs[buf][nh], wn * 32 + jj * 16 + l15, kk * 32 + lk8);
  };

  f32x4 acc[8][4] = {};
  auto MM = [&](int mh, int nh) {
    __builtin_amdgcn_s_setprio(1);
#pragma unroll
    for (int kk = 0; kk < 2; ++kk)
#pragma unroll
      for (int j = 0; j < 4; ++j)
#pragma unroll
        for (int jj = 0; jj < 2; ++jj)
          acc[mh * 4 + j][nh * 2 + jj] = __builtin_amdgcn_mfma_f32_16x16x32_bf16(
              a[j][kk], b[jj][kk], acc[mh * 4 + j][nh * 2 + jj], 0, 0, 0);
    __builtin_amdgcn_s_setprio(0);
  };
  auto BAR = [&]() {
    __builtin_amdgcn_s_barrier();
    asm volatile("" ::: "memory");
  };
  auto LGKM0 = [&]() {
    asm volatile("s_waitcnt lgkmcnt(0)" ::: "memory");
    __builtin_amdgcn_sched_barrier(0);
  };

  // prologue: tile0's 4 halves + A0,B1 of tile1 (8+4 loads); drain to 4
  STAGE_A(0, 0, 0);
  STAGE_B(0, 1, 0);
  STAGE_B(0, 0, 0);
  STAGE_A(0, 1, 0);
  STAGE_A(1, 0, 1);
  STAGE_B(1, 1, 1);
  asm volatile("s_waitcnt vmcnt(4)" ::: "memory");
  BAR();

  for (int T = 0; T < NT; ++T) {
    int cur = T & 1;
    // p0: quadrant (0,0)
    LDA(cur, 0);
    LDB(cur, 0);
    if (T + 1 < NT) STAGE_B(T + 1, 0, cur ^ 1);
    BAR(); LGKM0();
    MM(0, 0);
    BAR();
    // p1: (0,1)
    LDB(cur, 1);
    if (T + 1 < NT) STAGE_A(T + 1, 1, cur ^ 1);
    BAR(); LGKM0();
    MM(0, 1);
    BAR();
    // p2: (1,1)
    LDA(cur, 1);
    if (T + 2 < NT) STAGE_A(T + 2, 0, cur);
    BAR(); LGKM0();
    MM(1, 1);
    BAR();
    // p3: (1,0)
    LDB(cur, 0);
    if (T + 2 < NT) STAGE_B(T + 2, 1, cur);
    BAR(); LGKM0();
    MM(1, 0);
    if (T + 1 < NT) {
      if (T == NT - 2) {
        asm volatile("s_waitcnt vmcnt(0)" ::: "memory");
      } else {
        asm volatile("s_waitcnt vmcnt(4)" ::: "memory");
      }
    }
    BAR();
  }

  // epilogue
#pragma unroll
  for (int mi = 0; mi < 8; ++mi) {
#pragma unroll
    for (int ni = 0; ni < 4; ++ni) {
#pragma unroll
      for (int rr = 0; rr < 4; ++rr) {
        int gm = m0 + (mi >> 2) * 128 + wm * 64 + (mi & 3) * 16 + lr4 + rr;
        int gn = n0 + (ni >> 1) * 128 + wn * 32 + (ni & 1) * 16 + l15;
        float v = acc[mi][ni][rr];
        if constexpr (EPI == 0) {
          int which = gn >> 10, nc = gn & 1023;
          int h = nc >> 6, dh = nc & 63;
          int bb = gm >> 11, s = gm & 2047;
          ((uint16_t*)Cout)[((size_t)which * 32 + bb * 16 + h) * (S_ * 64) +
                            (size_t)s * 64 + dh] = f2bf(v);
        } else if constexpr (EPI == 2) {
          float u = v + bias[gn];
          float y = 0.7978845608028654f * (u + 0.044715f * u * u * u);
          float e = __expf(2.0f * y);
          float th = 1.0f - 2.0f / (e + 1.0f);  // tanh(y), inf-safe
          ((uint16_t*)Cout)[(size_t)gm * N + gn] = f2bf(0.5f * u * (1.0f + th));
        } else {
          unsafeAtomicAdd(&((float*)Cout)[(size_t)gm * N + gn], v);
        }
      }
    }
  }
}

// ---------- 128x128 2-phase GEMM (kept for Wo only; T1+T2, single-buffer) -----
template <int EPI>
__global__ __launch_bounds__(256) void gemm_bt(
    const uint16_t* __restrict__ A, const uint16_t* __restrict__ BT,
    void* __restrict__ Cout, const float* __restrict__ bias,
    const float* __restrict__ resid, int M, int N, int K) {
  __shared__ uint16_t Asm_[128 * 64];
  __shared__ uint16_t Bsm_[128 * 64];
  int t = threadIdx.x;
  int lane = t & 63, wid = t >> 6;
  int wr = wid >> 1, wc = wid & 1;
  int nwg = gridDim.x * gridDim.y;
  int bid = blockIdx.y * gridDim.x + blockIdx.x;
  int swz = (bid & 7) * (nwg >> 3) + (bid >> 3);
  int bx = swz % gridDim.x, by = swz / gridDim.x;
  int m0 = by * 128, n0 = bx * 128;
  int l15 = lane & 15, lk8 = (lane >> 4) * 8;
  f32x4 acc[4][4] = {};

  auto STAGE = [&](int k0) {
#pragma unroll
    for (int it = 0; it < 4; ++it) {
      int idx = it * 256 + t;
      int r = idx >> 3, slot = idx & 7;
      int c = (slot ^ (r & 7)) * 8;
      gload_lds16(A + (size_t)(m0 + r) * K + k0 + c, &Asm_[idx * 8]);
      gload_lds16(BT + (size_t)(n0 + r) * K + k0 + c, &Bsm_[idx * 8]);
    }
  };

  int niter = K >> 6;
  for (int ki = 0; ki < niter; ++ki) {
    __syncthreads();
    STAGE(ki * 64);
    __syncthreads();
#pragma unroll
    for (int kk = 0; kk < 2; ++kk) {
      bf16x8 a[4], b[4];
#pragma unroll
      for (int mi = 0; mi < 4; ++mi)
        a[mi] = *lds8p(Asm_, wr * 64 + mi * 16 + l15, kk * 32 + lk8);
#pragma unroll
      for (int ni = 0; ni < 4; ++ni)
        b[ni] = *lds8p(Bsm_, wc * 64 + ni * 16 + l15, kk * 32 + lk8);
#pragma unroll
      for (int mi = 0; mi < 4; ++mi)
#pragma unroll
        for (int ni = 0; ni < 4; ++ni)
          acc[mi][ni] = __builtin_amdgcn_mfma_f32_16x16x32_bf16(
              a[mi], b[ni], acc[mi][ni], 0, 0, 0);
    }
  }
  int lr4 = (lane >> 4) * 4;
#pragma unroll
  for (int mi = 0; mi < 4; ++mi) {
#pragma unroll
    for (int ni = 0; ni < 4; ++ni) {
#pragma unroll
      for (int r = 0; r < 4; ++r) {
        int gm = m0 + wr * 64 + mi * 16 + lr4 + r;
        int gn = n0 + wc * 64 + ni * 16 + l15;
        float v = acc[mi][ni][r];
        if constexpr (EPI == 1) {
          ((float*)Cout)[(size_t)gm * N + gn] =
              resid[(size_t)gm * N + gn] + v + bias[gn];
        }
      }
    }
  }
}

// ---------- flash causal attention, QBLK=64 (4 waves x 16 rows), KVBLK=64 ----------
__global__ __launch_bounds__(256) void attn_k(const uint16_t* __restrict__ Q,
                                              const uint16_t* __restrict__ Kv,
                                              const uint16_t* __restrict__ VT,
                                              uint16_t* __restrict__ ctx) {
  __shared__ uint16_t Ksm[2][64 * 64];
  __shared__ uint16_t Vsm[2][64 * 64];  // Vt tile: [dh][key]
  __shared__ uint16_t Psm[4][16 * 64];
  int bh = blockIdx.y;
  int t = threadIdx.x, lane = t & 63, wid = t >> 6;
  int l15 = lane & 15, lk8 = (lane >> 4) * 8, lr4 = (lane >> 4) * 4;

  auto STAGE = [&](int kt, int bufi) {
    int k0 = kt * 64;
#pragma unroll
    for (int it = 0; it < 2; ++it) {
      int idx = it * 256 + t;
      int r = idx >> 3, slot = idx & 7;
      int c = (slot ^ (r & 7)) * 8;
      gload_lds16(Kv + ((size_t)bh * S_ + k0 + r) * 64 + c, &Ksm[bufi][idx * 8]);
      gload_lds16(VT + ((size_t)bh * 64 + r) * S_ + k0 + c, &Vsm[bufi][idx * 8]);
    }
  };

  for (int half = 0; half < 2; ++half) {
    int qt = half ? 31 - blockIdx.x : blockIdx.x;
    int q0 = qt * 64;
    bf16x8 qf[2];
#pragma unroll
    for (int kk = 0; kk < 2; ++kk)
      qf[kk] = *reinterpret_cast<const bf16x8*>(
          &Q[((size_t)bh * S_ + q0 + wid * 16 + l15) * 64 + kk * 32 + lk8]);
    f32x4 o[4] = {};
    float mrow[4], lsum[4];
#pragma unroll
    for (int r = 0; r < 4; ++r) { mrow[r] = -3.0e38f; lsum[r] = 0.0f; }

    int nkt = qt + 1;
    STAGE(0, 0);
    for (int kt = 0; kt < nkt; ++kt) {
      int cur = kt & 1;
      if (kt + 1 < nkt) {
        STAGE(kt + 1, cur ^ 1);
        asm volatile("s_waitcnt vmcnt(4)" ::: "memory");
      } else {
        asm volatile("s_waitcnt vmcnt(0)" ::: "memory");
      }
      __builtin_amdgcn_s_barrier();
      asm volatile("" ::: "memory");
      __builtin_amdgcn_sched_barrier(0);
      const uint16_t* Kb = Ksm[cur];
      const uint16_t* Vb = Vsm[cur];

      f32x4 sf[4] = {};
#pragma unroll
      for (int kk = 0; kk < 2; ++kk)
#pragma unroll
        for (int nt = 0; nt < 4; ++nt) {
          bf16x8 kb = *lds8p(Kb, nt * 16 + l15, kk * 32 + lk8);
          sf[nt] = __builtin_amdgcn_mfma_f32_16x16x32_bf16(qf[kk], kb, sf[nt], 0, 0, 0);
        }
      float sv[4][4];
      if (kt == qt) {
#pragma unroll
        for (int nt = 0; nt < 4; ++nt)
#pragma unroll
          for (int r = 0; r < 4; ++r) {
            float s = sf[nt][r] * 0.125f;
            int key = nt * 16 + l15;
            int qr = wid * 16 + lr4 + r;
            sv[nt][r] = (key <= qr) ? s : -3.0e38f;
          }
      } else {
#pragma unroll
        for (int nt = 0; nt < 4; ++nt)
#pragma unroll
          for (int r = 0; r < 4; ++r) sv[nt][r] = sf[nt][r] * 0.125f;
      }
      float pmax[4];
#pragma unroll
      for (int r = 0; r < 4; ++r)
        pmax[r] = fmaxf(fmaxf(sv[0][r], sv[1][r]), fmaxf(sv[2][r], sv[3][r]));
#pragma unroll
      for (int off = 8; off >= 1; off >>= 1)
#pragma unroll
        for (int r = 0; r < 4; ++r)
          pmax[r] = fmaxf(pmax[r], __shfl_xor(pmax[r], off));
      float fac[4];
#pragma unroll
      for (int r = 0; r < 4; ++r) {
        float mn = fmaxf(mrow[r], pmax[r]);
        fac[r] = __expf(mrow[r] - mn);
        mrow[r] = mn;
        lsum[r] *= fac[r];
      }
#pragma unroll
      for (int dt = 0; dt < 4; ++dt)
#pragma unroll
        for (int r = 0; r < 4; ++r) o[dt][r] *= fac[r];
      float psum[4] = {0.0f, 0.0f, 0.0f, 0.0f};
#pragma unroll
      for (int nt = 0; nt < 4; ++nt)
#pragma unroll
        for (int r = 0; r < 4; ++r) {
          float p = __expf(sv[nt][r] - mrow[r]);
          psum[r] += p;
          int prow = lr4 + r, pcol = nt * 16 + l15;
          Psm[wid][prow * 64 + ((((pcol * 2) ^ ((prow & 7) << 4))) >> 1)] = f2bf(p);
        }
#pragma unroll
      for (int off = 8; off >= 1; off >>= 1)
#pragma unroll
        for (int r = 0; r < 4; ++r) psum[r] += __shfl_xor(psum[r], off);
#pragma unroll
      for (int r = 0; r < 4; ++r) lsum[r] += psum[r];
#pragma unroll
      for (int kk = 0; kk < 2; ++kk) {
        bf16x8 pa = *lds8p(Psm[wid], l15, kk * 32 + lk8);
#pragma unroll
        for (int dt = 0; dt < 4; ++dt) {
          bf16x8 vb = *lds8p(Vb, dt * 16 + l15, kk * 32 + lk8);
          o[dt] = __builtin_amdgcn_mfma_f32_16x16x32_bf16(pa, vb, o[dt], 0, 0, 0);
        }
      }
      asm volatile("s_waitcnt lgkmcnt(0)" ::: "memory");
      __builtin_amdgcn_sched_barrier(0);
      __builtin_amdgcn_s_barrier();
      asm volatile("" ::: "memory");
    }
    int b = bh >> 4, h = bh & 15;
#pragma unroll
    for (int dt = 0; dt < 4; ++dt)
#pragma unroll
      for (int r = 0; r < 4; ++r) {
        int s = q0 + wid * 16 + lr4 + r;
        int dh = dt * 16 + l15;
        ctx[((size_t)(b * S_ + s)) * D_ + h * 64 + dh] = f2bf(o[dt][r] / lsum[r]);
      }
  }
}

extern "C" void kernel_launch(void* const* d_in, const int* in_sizes, int n_in,
                              void* d_out, int out_size, void* d_ws, size_t ws_size,
                              hipStream_t stream) {
  const float* x    = (const float*)d_in[0];
  const float* Wq   = (const float*)d_in[1];
  const float* Wk   = (const float*)d_in[2];
  const float* Wv   = (const float*)d_in[3];
  const float* Wo   = (const float*)d_in[4];
  const float* bo   = (const float*)d_in[5];
  const float* W1   = (const float*)d_in[6];
  const float* b1   = (const float*)d_in[7];
  const float* W2   = (const float*)d_in[8];
  const float* b2   = (const float*)d_in[9];
  const float* ln1s = (const float*)d_in[10];
  const float* ln1b = (const float*)d_in[11];
  const float* ln2s = (const float*)d_in[12];
  const float* ln2b = (const float*)d_in[13];
  float* out = (float*)d_out;
  char* ws = (char*)d_ws;

  const size_t MB = 1024 * 1024;
  uint16_t* WQKVT = (uint16_t*)(ws + 0);        // 6 MB  (3072 x 1024)
  uint16_t* WOT   = (uint16_t*)(ws + 6 * MB);   // 2 MB  (1024 x 1024)
  uint16_t* W1T   = (uint16_t*)(ws + 8 * MB);   // 8 MB  (4096 x 1024)
  uint16_t* W2T   = (uint16_t*)(ws + 16 * MB);  // 8 MB  (1024 x 4096)
  uint16_t* H1    = (uint16_t*)(ws + 24 * MB);  // 8 MB  (LN1 out; reused for LN2 out)
  float*    X1    = (float*)(ws + 32 * MB);     // 16 MB (attn residual, f32)
  uint16_t* QKV   = (uint16_t*)(ws + 48 * MB);  // 24 MB (q,k,v in (bh,s,dh))
  uint16_t* VTb   = (uint16_t*)(ws + 72 * MB);  // 8 MB  (v transposed (bh,dh,s))
  uint16_t* CTX   = (uint16_t*)(ws + 80 * MB);  // 8 MB
  uint16_t* FFH   = (uint16_t*)(ws + 48 * MB);  // 32 MB (reuses dead QKV/VT)

  dim3 b32x8(32, 8);
  wconv_t<<<dim3(32, 32), b32x8, 0, stream>>>(Wq, WQKVT, 1024, 1024);
  wconv_t<<<dim3(32, 32), b32x8, 0, stream>>>(Wk, WQKVT + 1024 * 1024, 1024, 1024);
  wconv_t<<<dim3(32, 32), b32x8, 0, stream>>>(Wv, WQKVT + 2 * 1024 * 1024, 1024, 1024);
  wconv_t<<<dim3(32, 32), b32x8, 0, stream>>>(Wo, WOT, 1024, 1024);
  wconv_t<<<dim3(128, 32), b32x8, 0, stream>>>(W1, W1T, 1024, 4096);
  wconv_t<<<dim3(32, 128), b32x8, 0, stream>>>(W2, W2T, 4096, 1024);

  // LN1 -> h (bf16)
  ln_k<<<M_, 256, 0, stream>>>(x, ln1s, ln1b, H1);
  // QKV projections (fused N=3072), 256^2 8-phase, head-split epilogue
  gemm8<0><<<dim3(12, 16), 512, 0, stream>>>(H1, WQKVT, QKV, nullptr, M_, 3072, 1024);
  const uint16_t* Qp = QKV;
  const uint16_t* Kp = QKV + (size_t)32 * S_ * 64;
  const uint16_t* Vp = QKV + (size_t)64 * S_ * 64;
  vtrans_k<<<dim3(64, 2, 32), b32x8, 0, stream>>>(Vp, VTb);
  // flash causal attention (paired q-tiles)
  attn_k<<<dim3(16, 32), 256, 0, stream>>>(Qp, Kp, VTb, CTX);
  // Wo projection + bias + residual -> X1 (f32), 128^2 path
  gemm_bt<1><<<dim3(8, 32), 256, 0, stream>>>(CTX, WOT, X1, bo, x, M_, 1024, 1024);
  // LN2 -> h2 (bf16, reuse H1)
  ln_k<<<M_, 256, 0, stream>>>(X1, ln2s, ln2b, H1);
  // FFN1 + GELU -> FFH (bf16), 256^2 8-phase
  gemm8<2><<<dim3(16, 16), 512, 0, stream>>>(H1, W1T, FFH, b1, M_, 4096, 1024);
  // FFN2 split-K=4, 256^2 8-phase: out = X1 + b2, then atomicAdd partials
  initout_k<<<M_, 256, 0, stream>>>(X1, b2, out);
  gemm8<3><<<dim3(4, 16, 4), 512, 0, stream>>>(FFH, W2T, out, nullptr, M_, 1024, 4096);
}

// Round 7
// 265.479 us; speedup vs baseline: 1.2731x; 1.1342x over previous
//
#include <hip/hip_runtime.h>
#include <hip/hip_bf16.h>
#include <stdint.h>

#define B_   2
#define S_   2048
#define D_   1024
#define H_   16
#define DH_  64
#define HID_ 4096
#define M_   4096  // B_*S_

typedef __bf16 bf16x8 __attribute__((ext_vector_type(8)));
typedef float  f32x4  __attribute__((ext_vector_type(4)));

typedef const uint32_t __attribute__((address_space(1))) u32g;
typedef uint32_t       __attribute__((address_space(3))) u32l;

__device__ __forceinline__ uint16_t f2bf(float f) {
  uint32_t u = __builtin_bit_cast(uint32_t, f);
  u += 0x7FFFu + ((u >> 16) & 1u);   // RNE
  return (uint16_t)(u >> 16);
}

__device__ __forceinline__ float bf2f(uint16_t u) {
  return __builtin_bit_cast(float, (uint32_t)u << 16);
}

__device__ __forceinline__ void gload_lds16(const void* g, void* l) {
  __builtin_amdgcn_global_load_lds((u32g*)g, (u32l*)l, 16, 0, 0);
}

// swizzled LDS 16B read: row-major [*][64] bf16 tile, byte ^= (row&7)<<4
__device__ __forceinline__ const bf16x8* lds8p(const uint16_t* base, int row,
                                               int cole) {
  int byt = (cole * 2) ^ ((row & 7) << 4);
  return reinterpret_cast<const bf16x8*>(base + row * 64 + (byt >> 1));
}

// ---------- weight convert + transpose: W (K,N) f32 -> WT (N,K) bf16 ----------
__global__ void wconv_t(const float* __restrict__ W, uint16_t* __restrict__ WT,
                        int K, int N) {
  __shared__ float tile[32][33];
  int n0 = blockIdx.x * 32, k0 = blockIdx.y * 32;
  int tx = threadIdx.x, ty = threadIdx.y;  // (32,8)
#pragma unroll
  for (int i = 0; i < 4; ++i)
    tile[ty + i * 8][tx] = W[(size_t)(k0 + ty + i * 8) * N + n0 + tx];
  __syncthreads();
#pragma unroll
  for (int i = 0; i < 4; ++i)
    WT[(size_t)(n0 + ty + i * 8) * K + k0 + tx] = f2bf(tile[tx][ty + i * 8]);
}

// ---------- layernorm: f32 row (1024) -> bf16 ----------
__global__ __launch_bounds__(256) void ln_k(const float* __restrict__ x,
                                            const float* __restrict__ sc,
                                            const float* __restrict__ sh,
                                            uint16_t* __restrict__ out) {
  int row = blockIdx.x;
  int t = threadIdx.x;
  float4 v = reinterpret_cast<const float4*>(x + (size_t)row * D_)[t];
  float s = v.x + v.y + v.z + v.w;
  float ss = v.x * v.x + v.y * v.y + v.z * v.z + v.w * v.w;
#pragma unroll
  for (int off = 32; off >= 1; off >>= 1) {
    s += __shfl_xor(s, off);
    ss += __shfl_xor(ss, off);
  }
  __shared__ float red[8];
  int wid = t >> 6, lane = t & 63;
  if (lane == 0) { red[wid] = s; red[wid + 4] = ss; }
  __syncthreads();
  s = red[0] + red[1] + red[2] + red[3];
  ss = red[4] + red[5] + red[6] + red[7];
  float mean = s * (1.0f / D_);
  float var = ss * (1.0f / D_) - mean * mean;
  float rstd = rsqrtf(var + 1e-5f);
  float4 g = reinterpret_cast<const float4*>(sc)[t];
  float4 b = reinterpret_cast<const float4*>(sh)[t];
  ushort4 o;
  o.x = f2bf(g.x * (v.x - mean) * rstd + b.x);
  o.y = f2bf(g.y * (v.y - mean) * rstd + b.y);
  o.z = f2bf(g.z * (v.z - mean) * rstd + b.z);
  o.w = f2bf(g.w * (v.w - mean) * rstd + b.w);
  reinterpret_cast<ushort4*>(out + (size_t)row * D_)[t] = o;
}

// ---------- out = resid + bias + sum of 4 bf16 partials (split-K reduce) ------
__global__ __launch_bounds__(256) void reduce4_k(
    const uint16_t* __restrict__ P0, const uint16_t* __restrict__ P1,
    const uint16_t* __restrict__ P2, const uint16_t* __restrict__ P3,
    const float* __restrict__ resid, const float* __restrict__ bias,
    float* __restrict__ out) {
  int row = blockIdx.x, t = threadIdx.x;
  size_t base = (size_t)row * D_ + t * 4;
  float4 r = *reinterpret_cast<const float4*>(resid + base);
  float4 b = reinterpret_cast<const float4*>(bias)[t];
  ushort4 u0 = *reinterpret_cast<const ushort4*>(P0 + base);
  ushort4 u1 = *reinterpret_cast<const ushort4*>(P1 + base);
  ushort4 u2 = *reinterpret_cast<const ushort4*>(P2 + base);
  ushort4 u3 = *reinterpret_cast<const ushort4*>(P3 + base);
  float4 o;
  o.x = r.x + b.x + bf2f(u0.x) + bf2f(u1.x) + bf2f(u2.x) + bf2f(u3.x);
  o.y = r.y + b.y + bf2f(u0.y) + bf2f(u1.y) + bf2f(u2.y) + bf2f(u3.y);
  o.z = r.z + b.z + bf2f(u0.z) + bf2f(u1.z) + bf2f(u2.z) + bf2f(u3.z);
  o.w = r.w + b.w + bf2f(u0.w) + bf2f(u1.w) + bf2f(u2.w) + bf2f(u3.w);
  *reinterpret_cast<float4*>(out + base) = o;
}

// ---------- transpose V (bh,s,dh) -> VT (bh,dh,s), bf16 ----------
__global__ void vtrans_k(const uint16_t* __restrict__ V, uint16_t* __restrict__ VT) {
  __shared__ uint16_t tile[32][33];
  int s0 = blockIdx.x * 32, d0 = blockIdx.y * 32, bh = blockIdx.z;
  int tx = threadIdx.x, ty = threadIdx.y;  // (32,8)
  const uint16_t* vb = V + (size_t)bh * S_ * DH_;
  uint16_t* vtb = VT + (size_t)bh * DH_ * S_;
#pragma unroll
  for (int i = 0; i < 4; ++i)
    tile[ty + i * 8][tx] = vb[(size_t)(s0 + ty + i * 8) * DH_ + d0 + tx];
  __syncthreads();
#pragma unroll
  for (int i = 0; i < 4; ++i)
    vtb[(size_t)(d0 + ty + i * 8) * S_ + s0 + tx] = tile[tx][ty + i * 8];
}

// ================== 256x256 8-phase GEMM (T2+T3+T4+T5), BK=64 ==================
// A (M,K) bf16 x BT (N,K) bf16. 512 threads = 8 waves (2M x 4N); per-wave
// output 128x64 (8x4 16x16 frags). LDS 128 KiB: A/B x 2 dbuf x 2 M-halves of
// 128x64 bf16, XOR-swizzled via pre-swizzled global source. Schedule per
// K-tile T (4 phases, quadrants (mh,nh) = (0,0),(0,1),(1,1),(1,0)):
//   p0: ds A0+B0 | stage B0(T+1)->buf^1 | bar | lgkm0 | 16 MFMA | bar
//   p1: ds B1    | stage A1(T+1)->buf^1 | bar | lgkm0 | 16 MFMA | bar
//   p2: ds A1    | stage A0(T+2)->buf   | bar | lgkm0 | 16 MFMA | bar
//   p3: ds B0    | stage B1(T+2)->buf   | bar | lgkm0 | 16 MFMA | vmcnt(4) bar
// vmcnt(4) = 2 half-tiles in flight; vmcnt(0) before the last tile (T4).
// setprio around MFMA (T5). Split-K via gridDim.z writes PLAIN bf16 partials
// (R6 post-mortem: the 16.7M-dword device-atomic epilogue was the FFN2 wall).
// EPI 0: qkv head-split bf16; 2: gelu bf16; 3: bf16 partial store per z-buffer
template <int EPI>
__global__ __launch_bounds__(512, 2) void gemm8(
    const uint16_t* __restrict__ A, const uint16_t* __restrict__ BT,
    void* __restrict__ Cout, const float* __restrict__ bias,
    uint16_t* __restrict__ P0, uint16_t* __restrict__ P1,
    uint16_t* __restrict__ P2, uint16_t* __restrict__ P3,
    int M, int N, int K) {
  __shared__ uint16_t As[2][2][128 * 64];
  __shared__ uint16_t Bs[2][2][128 * 64];
  int t = threadIdx.x;
  int lane = t & 63, wid = t >> 6;
  int wm = wid >> 2, wn = wid & 3;
  int l15 = lane & 15, lk8 = (lane >> 4) * 8, lr4 = (lane >> 4) * 4;
  // XCD-aware bijective swizzle over (x,y); all grids have nwg_xy % 8 == 0
  int gx = gridDim.x;
  int nwg = gx * gridDim.y;
  int bid = blockIdx.y * gx + blockIdx.x;
  int swz = (bid & 7) * (nwg >> 3) + (bid >> 3);
  int bx = swz % gx, by = swz / gx;
  int m0 = by * 256, n0 = bx * 256;
  int ksz = K / gridDim.z;
  int kbeg = blockIdx.z * ksz;
  int NT = ksz >> 6;

  // staging: half-tile 128x64 bf16 = 16 KB = 512 thr x 2 x 16 B
  int r0 = t >> 3, slot0 = t & 7;
  int scol = (slot0 ^ (r0 & 7)) * 8;  // pre-swizzled source col (involution)

  auto STAGE_A = [&](int kt, int half, int buf) {
    const uint16_t* src =
        A + (size_t)(m0 + half * 128 + r0) * K + kbeg + kt * 64 + scol;
    uint16_t* dst = &As[buf][half][t * 8];
    gload_lds16(src, dst);
    gload_lds16(src + (size_t)64 * K, dst + 4096);
  };
  auto STAGE_B = [&](int kt, int half, int buf) {
    const uint16_t* src =
        BT + (size_t)(n0 + half * 128 + r0) * K + kbeg + kt * 64 + scol;
    uint16_t* dst = &Bs[buf][half][t * 8];
    gload_lds16(src, dst);
    gload_lds16(src + (size_t)64 * K, dst + 4096);
  };

  bf16x8 a[4][2], b[2][2];
  auto LDA = [&](int buf, int mh) {
#pragma unroll
    for (int j = 0; j < 4; ++j)
#pragma unroll
      for (int kk = 0; kk < 2; ++kk)
        a[j][kk] = *lds8p(As[buf][mh], wm * 64 + j * 16 + l15, kk * 32 + lk8);
  };
  auto LDB = [&](int buf, int nh) {
#pragma unroll
    for (int jj = 0; jj < 2; ++jj)
#pragma unroll
      for (int kk = 0; kk < 2; ++kk)
        b[jj][kk] = *lds8p(Bs[buf][nh], wn * 32 + jj * 16 + l15, kk * 32 + lk8);
  };

  f32x4 acc[8][4] = {};
  auto MM = [&](int mh, int nh) {
    __builtin_amdgcn_s_setprio(1);
#pragma unroll
    for (int kk = 0; kk < 2; ++kk)
#pragma unroll
      for (int j = 0; j < 4; ++j)
#pragma unroll
        for (int jj = 0; jj < 2; ++jj)
          acc[mh * 4 + j][nh * 2 + jj] = __builtin_amdgcn_mfma_f32_16x16x32_bf16(
              a[j][kk], b[jj][kk], acc[mh * 4 + j][nh * 2 + jj], 0, 0, 0);
    __builtin_amdgcn_s_setprio(0);
  };
  auto BAR = [&]() {
    __builtin_amdgcn_s_barrier();
    asm volatile("" ::: "memory");
  };
  auto LGKM0 = [&]() {
    asm volatile("s_waitcnt lgkmcnt(0)" ::: "memory");
    __builtin_amdgcn_sched_barrier(0);
  };

  // prologue: tile0's 4 halves + A0,B1 of tile1 (8+4 loads); drain to 4
  STAGE_A(0, 0, 0);
  STAGE_B(0, 1, 0);
  STAGE_B(0, 0, 0);
  STAGE_A(0, 1, 0);
  STAGE_A(1, 0, 1);
  STAGE_B(1, 1, 1);
  asm volatile("s_waitcnt vmcnt(4)" ::: "memory");
  BAR();

  for (int T = 0; T < NT; ++T) {
    int cur = T & 1;
    // p0: quadrant (0,0)
    LDA(cur, 0);
    LDB(cur, 0);
    if (T + 1 < NT) STAGE_B(T + 1, 0, cur ^ 1);
    BAR(); LGKM0();
    MM(0, 0);
    BAR();
    // p1: (0,1)
    LDB(cur, 1);
    if (T + 1 < NT) STAGE_A(T + 1, 1, cur ^ 1);
    BAR(); LGKM0();
    MM(0, 1);
    BAR();
    // p2: (1,1)
    LDA(cur, 1);
    if (T + 2 < NT) STAGE_A(T + 2, 0, cur);
    BAR(); LGKM0();
    MM(1, 1);
    BAR();
    // p3: (1,0)
    LDB(cur, 0);
    if (T + 2 < NT) STAGE_B(T + 2, 1, cur);
    BAR(); LGKM0();
    MM(1, 0);
    if (T + 1 < NT) {
      if (T == NT - 2) {
        asm volatile("s_waitcnt vmcnt(0)" ::: "memory");
      } else {
        asm volatile("s_waitcnt vmcnt(4)" ::: "memory");
      }
    }
    BAR();
  }

  // epilogue
  uint16_t* Pz = nullptr;
  if constexpr (EPI == 3) {
    int z = blockIdx.z;
    Pz = (z == 0) ? P0 : (z == 1) ? P1 : (z == 2) ? P2 : P3;
  }
#pragma unroll
  for (int mi = 0; mi < 8; ++mi) {
#pragma unroll
    for (int ni = 0; ni < 4; ++ni) {
#pragma unroll
      for (int rr = 0; rr < 4; ++rr) {
        int gm = m0 + (mi >> 2) * 128 + wm * 64 + (mi & 3) * 16 + lr4 + rr;
        int gn = n0 + (ni >> 1) * 128 + wn * 32 + (ni & 1) * 16 + l15;
        float v = acc[mi][ni][rr];
        if constexpr (EPI == 0) {
          int which = gn >> 10, nc = gn & 1023;
          int h = nc >> 6, dh = nc & 63;
          int bb = gm >> 11, s = gm & 2047;
          ((uint16_t*)Cout)[((size_t)which * 32 + bb * 16 + h) * (S_ * 64) +
                            (size_t)s * 64 + dh] = f2bf(v);
        } else if constexpr (EPI == 2) {
          float u = v + bias[gn];
          float y = 0.7978845608028654f * (u + 0.044715f * u * u * u);
          float e = __expf(2.0f * y);
          float th = 1.0f - 2.0f / (e + 1.0f);  // tanh(y), inf-safe
          ((uint16_t*)Cout)[(size_t)gm * N + gn] = f2bf(0.5f * u * (1.0f + th));
        } else {
          Pz[(size_t)gm * N + gn] = f2bf(v);
        }
      }
    }
  }
}

// ---------- 128x128 2-phase GEMM (kept for Wo only; T1+T2, single-buffer) -----
template <int EPI>
__global__ __launch_bounds__(256) void gemm_bt(
    const uint16_t* __restrict__ A, const uint16_t* __restrict__ BT,
    void* __restrict__ Cout, const float* __restrict__ bias,
    const float* __restrict__ resid, int M, int N, int K) {
  __shared__ uint16_t Asm_[128 * 64];
  __shared__ uint16_t Bsm_[128 * 64];
  int t = threadIdx.x;
  int lane = t & 63, wid = t >> 6;
  int wr = wid >> 1, wc = wid & 1;
  int nwg = gridDim.x * gridDim.y;
  int bid = blockIdx.y * gridDim.x + blockIdx.x;
  int swz = (bid & 7) * (nwg >> 3) + (bid >> 3);
  int bx = swz % gridDim.x, by = swz / gridDim.x;
  int m0 = by * 128, n0 = bx * 128;
  int l15 = lane & 15, lk8 = (lane >> 4) * 8;
  f32x4 acc[4][4] = {};

  auto STAGE = [&](int k0) {
#pragma unroll
    for (int it = 0; it < 4; ++it) {
      int idx = it * 256 + t;
      int r = idx >> 3, slot = idx & 7;
      int c = (slot ^ (r & 7)) * 8;
      gload_lds16(A + (size_t)(m0 + r) * K + k0 + c, &Asm_[idx * 8]);
      gload_lds16(BT + (size_t)(n0 + r) * K + k0 + c, &Bsm_[idx * 8]);
    }
  };

  int niter = K >> 6;
  for (int ki = 0; ki < niter; ++ki) {
    __syncthreads();
    STAGE(ki * 64);
    __syncthreads();
#pragma unroll
    for (int kk = 0; kk < 2; ++kk) {
      bf16x8 a[4], b[4];
#pragma unroll
      for (int mi = 0; mi < 4; ++mi)
        a[mi] = *lds8p(Asm_, wr * 64 + mi * 16 + l15, kk * 32 + lk8);
#pragma unroll
      for (int ni = 0; ni < 4; ++ni)
        b[ni] = *lds8p(Bsm_, wc * 64 + ni * 16 + l15, kk * 32 + lk8);
#pragma unroll
      for (int mi = 0; mi < 4; ++mi)
#pragma unroll
        for (int ni = 0; ni < 4; ++ni)
          acc[mi][ni] = __builtin_amdgcn_mfma_f32_16x16x32_bf16(
              a[mi], b[ni], acc[mi][ni], 0, 0, 0);
    }
  }
  int lr4 = (lane >> 4) * 4;
#pragma unroll
  for (int mi = 0; mi < 4; ++mi) {
#pragma unroll
    for (int ni = 0; ni < 4; ++ni) {
#pragma unroll
      for (int r = 0; r < 4; ++r) {
        int gm = m0 + wr * 64 + mi * 16 + lr4 + r;
        int gn = n0 + wc * 64 + ni * 16 + l15;
        float v = acc[mi][ni][r];
        if constexpr (EPI == 1) {
          ((float*)Cout)[(size_t)gm * N + gn] =
              resid[(size_t)gm * N + gn] + v + bias[gn];
        }
      }
    }
  }
}

// ---------- flash causal attention, QBLK=64 (4 waves x 16 rows), KVBLK=64 ----------
__global__ __launch_bounds__(256) void attn_k(const uint16_t* __restrict__ Q,
                                              const uint16_t* __restrict__ Kv,
                                              const uint16_t* __restrict__ VT,
                                              uint16_t* __restrict__ ctx) {
  __shared__ uint16_t Ksm[2][64 * 64];
  __shared__ uint16_t Vsm[2][64 * 64];  // Vt tile: [dh][key]
  __shared__ uint16_t Psm[4][16 * 64];
  int bh = blockIdx.y;
  int t = threadIdx.x, lane = t & 63, wid = t >> 6;
  int l15 = lane & 15, lk8 = (lane >> 4) * 8, lr4 = (lane >> 4) * 4;

  auto STAGE = [&](int kt, int bufi) {
    int k0 = kt * 64;
#pragma unroll
    for (int it = 0; it < 2; ++it) {
      int idx = it * 256 + t;
      int r = idx >> 3, slot = idx & 7;
      int c = (slot ^ (r & 7)) * 8;
      gload_lds16(Kv + ((size_t)bh * S_ + k0 + r) * 64 + c, &Ksm[bufi][idx * 8]);
      gload_lds16(VT + ((size_t)bh * 64 + r) * S_ + k0 + c, &Vsm[bufi][idx * 8]);
    }
  };

  for (int half = 0; half < 2; ++half) {
    int qt = half ? 31 - blockIdx.x : blockIdx.x;
    int q0 = qt * 64;
    bf16x8 qf[2];
#pragma unroll
    for (int kk = 0; kk < 2; ++kk)
      qf[kk] = *reinterpret_cast<const bf16x8*>(
          &Q[((size_t)bh * S_ + q0 + wid * 16 + l15) * 64 + kk * 32 + lk8]);
    f32x4 o[4] = {};
    float mrow[4], lsum[4];
#pragma unroll
    for (int r = 0; r < 4; ++r) { mrow[r] = -3.0e38f; lsum[r] = 0.0f; }

    int nkt = qt + 1;
    STAGE(0, 0);
    for (int kt = 0; kt < nkt; ++kt) {
      int cur = kt & 1;
      if (kt + 1 < nkt) {
        STAGE(kt + 1, cur ^ 1);
        asm volatile("s_waitcnt vmcnt(4)" ::: "memory");
      } else {
        asm volatile("s_waitcnt vmcnt(0)" ::: "memory");
      }
      __builtin_amdgcn_s_barrier();
      asm volatile("" ::: "memory");
      __builtin_amdgcn_sched_barrier(0);
      const uint16_t* Kb = Ksm[cur];
      const uint16_t* Vb = Vsm[cur];

      f32x4 sf[4] = {};
#pragma unroll
      for (int kk = 0; kk < 2; ++kk)
#pragma unroll
        for (int nt = 0; nt < 4; ++nt) {
          bf16x8 kb = *lds8p(Kb, nt * 16 + l15, kk * 32 + lk8);
          sf[nt] = __builtin_amdgcn_mfma_f32_16x16x32_bf16(qf[kk], kb, sf[nt], 0, 0, 0);
        }
      float sv[4][4];
      if (kt == qt) {
#pragma unroll
        for (int nt = 0; nt < 4; ++nt)
#pragma unroll
          for (int r = 0; r < 4; ++r) {
            float s = sf[nt][r] * 0.125f;
            int key = nt * 16 + l15;
            int qr = wid * 16 + lr4 + r;
            sv[nt][r] = (key <= qr) ? s : -3.0e38f;
          }
      } else {
#pragma unroll
        for (int nt = 0; nt < 4; ++nt)
#pragma unroll
          for (int r = 0; r < 4; ++r) sv[nt][r] = sf[nt][r] * 0.125f;
      }
      float pmax[4];
#pragma unroll
      for (int r = 0; r < 4; ++r)
        pmax[r] = fmaxf(fmaxf(sv[0][r], sv[1][r]), fmaxf(sv[2][r], sv[3][r]));
#pragma unroll
      for (int off = 8; off >= 1; off >>= 1)
#pragma unroll
        for (int r = 0; r < 4; ++r)
          pmax[r] = fmaxf(pmax[r], __shfl_xor(pmax[r], off));
      float fac[4];
#pragma unroll
      for (int r = 0; r < 4; ++r) {
        float mn = fmaxf(mrow[r], pmax[r]);
        fac[r] = __expf(mrow[r] - mn);
        mrow[r] = mn;
        lsum[r] *= fac[r];
      }
#pragma unroll
      for (int dt = 0; dt < 4; ++dt)
#pragma unroll
        for (int r = 0; r < 4; ++r) o[dt][r] *= fac[r];
      float psum[4] = {0.0f, 0.0f, 0.0f, 0.0f};
#pragma unroll
      for (int nt = 0; nt < 4; ++nt)
#pragma unroll
        for (int r = 0; r < 4; ++r) {
          float p = __expf(sv[nt][r] - mrow[r]);
          psum[r] += p;
          int prow = lr4 + r, pcol = nt * 16 + l15;
          Psm[wid][prow * 64 + ((((pcol * 2) ^ ((prow & 7) << 4))) >> 1)] = f2bf(p);
        }
#pragma unroll
      for (int off = 8; off >= 1; off >>= 1)
#pragma unroll
        for (int r = 0; r < 4; ++r) psum[r] += __shfl_xor(psum[r], off);
#pragma unroll
      for (int r = 0; r < 4; ++r) lsum[r] += psum[r];
#pragma unroll
      for (int kk = 0; kk < 2; ++kk) {
        bf16x8 pa = *lds8p(Psm[wid], l15, kk * 32 + lk8);
#pragma unroll
        for (int dt = 0; dt < 4; ++dt) {
          bf16x8 vb = *lds8p(Vb, dt * 16 + l15, kk * 32 + lk8);
          o[dt] = __builtin_amdgcn_mfma_f32_16x16x32_bf16(pa, vb, o[dt], 0, 0, 0);
        }
      }
      asm volatile("s_waitcnt lgkmcnt(0)" ::: "memory");
      __builtin_amdgcn_sched_barrier(0);
      __builtin_amdgcn_s_barrier();
      asm volatile("" ::: "memory");
    }
    int b = bh >> 4, h = bh & 15;
#pragma unroll
    for (int dt = 0; dt < 4; ++dt)
#pragma unroll
      for (int r = 0; r < 4; ++r) {
        int s = q0 + wid * 16 + lr4 + r;
        int dh = dt * 16 + l15;
        ctx[((size_t)(b * S_ + s)) * D_ + h * 64 + dh] = f2bf(o[dt][r] / lsum[r]);
      }
  }
}

extern "C" void kernel_launch(void* const* d_in, const int* in_sizes, int n_in,
                              void* d_out, int out_size, void* d_ws, size_t ws_size,
                              hipStream_t stream) {
  const float* x    = (const float*)d_in[0];
  const float* Wq   = (const float*)d_in[1];
  const float* Wk   = (const float*)d_in[2];
  const float* Wv   = (const float*)d_in[3];
  const float* Wo   = (const float*)d_in[4];
  const float* bo   = (const float*)d_in[5];
  const float* W1   = (const float*)d_in[6];
  const float* b1   = (const float*)d_in[7];
  const float* W2   = (const float*)d_in[8];
  const float* b2   = (const float*)d_in[9];
  const float* ln1s = (const float*)d_in[10];
  const float* ln1b = (const float*)d_in[11];
  const float* ln2s = (const float*)d_in[12];
  const float* ln2b = (const float*)d_in[13];
  float* out = (float*)d_out;
  char* ws = (char*)d_ws;

  const size_t MB = 1024 * 1024;
  uint16_t* WQKVT = (uint16_t*)(ws + 0);        // 6 MB  (3072 x 1024)
  uint16_t* WOT   = (uint16_t*)(ws + 6 * MB);   // 2 MB  (1024 x 1024)
  uint16_t* W1T   = (uint16_t*)(ws + 8 * MB);   // 8 MB  (4096 x 1024)
  uint16_t* W2T   = (uint16_t*)(ws + 16 * MB);  // 8 MB  (1024 x 4096)
  uint16_t* H1    = (uint16_t*)(ws + 24 * MB);  // 8 MB  (LN1 out; reused for LN2 out)
  float*    X1    = (float*)(ws + 32 * MB);     // 16 MB (attn residual, f32)
  uint16_t* QKV   = (uint16_t*)(ws + 48 * MB);  // 24 MB (q,k,v in (bh,s,dh))
  uint16_t* VTb   = (uint16_t*)(ws + 72 * MB);  // 8 MB  (v transposed (bh,dh,s))
  uint16_t* CTX   = (uint16_t*)(ws + 80 * MB);  // 8 MB
  uint16_t* FFH   = (uint16_t*)(ws + 48 * MB);  // 32 MB (reuses dead QKV/VT, 48-80)
  // split-K bf16 partials (8 MB each), placed in regions dead by FFN2 time:
  uint16_t* SP0   = (uint16_t*)(ws + 0);        // over WQKVT+WOT (dead after Wo)
  uint16_t* SP1   = (uint16_t*)(ws + 8 * MB);   // over W1T (dead after FFN1)
  uint16_t* SP2   = (uint16_t*)(ws + 24 * MB);  // over H1 (dead after FFN1)
  uint16_t* SP3   = (uint16_t*)(ws + 80 * MB);  // over CTX (dead after Wo)

  dim3 b32x8(32, 8);
  wconv_t<<<dim3(32, 32), b32x8, 0, stream>>>(Wq, WQKVT, 1024, 1024);
  wconv_t<<<dim3(32, 32), b32x8, 0, stream>>>(Wk, WQKVT + 1024 * 1024, 1024, 1024);
  wconv_t<<<dim3(32, 32), b32x8, 0, stream>>>(Wv, WQKVT + 2 * 1024 * 1024, 1024, 1024);
  wconv_t<<<dim3(32, 32), b32x8, 0, stream>>>(Wo, WOT, 1024, 1024);
  wconv_t<<<dim3(128, 32), b32x8, 0, stream>>>(W1, W1T, 1024, 4096);
  wconv_t<<<dim3(32, 128), b32x8, 0, stream>>>(W2, W2T, 4096, 1024);

  // LN1 -> h (bf16)
  ln_k<<<M_, 256, 0, stream>>>(x, ln1s, ln1b, H1);
  // QKV projections (fused N=3072), 256^2 8-phase, head-split epilogue
  gemm8<0><<<dim3(12, 16), 512, 0, stream>>>(H1, WQKVT, QKV, nullptr,
                                             nullptr, nullptr, nullptr, nullptr,
                                             M_, 3072, 1024);
  const uint16_t* Qp = QKV;
  const uint16_t* Kp = QKV + (size_t)32 * S_ * 64;
  const uint16_t* Vp = QKV + (size_t)64 * S_ * 64;
  vtrans_k<<<dim3(64, 2, 32), b32x8, 0, stream>>>(Vp, VTb);
  // flash causal attention (paired q-tiles)
  attn_k<<<dim3(16, 32), 256, 0, stream>>>(Qp, Kp, VTb, CTX);
  // Wo projection + bias + residual -> X1 (f32), 128^2 path
  gemm_bt<1><<<dim3(8, 32), 256, 0, stream>>>(CTX, WOT, X1, bo, x, M_, 1024, 1024);
  // LN2 -> h2 (bf16, reuse H1)
  ln_k<<<M_, 256, 0, stream>>>(X1, ln2s, ln2b, H1);
  // FFN1 + GELU -> FFH (bf16), 256^2 8-phase
  gemm8<2><<<dim3(16, 16), 512, 0, stream>>>(H1, W1T, FFH, b1,
                                             nullptr, nullptr, nullptr, nullptr,
                                             M_, 4096, 1024);
  // FFN2 split-K=4, 256^2 8-phase: bf16 partials (plain stores, no atomics)
  gemm8<3><<<dim3(4, 16, 4), 512, 0, stream>>>(FFH, W2T, nullptr, nullptr,
                                               SP0, SP1, SP2, SP3,
                                               M_, 1024, 4096);
  // out = X1 + b2 + sum(partials)
  reduce4_k<<<M_, 256, 0, stream>>>(SP0, SP1, SP2, SP3, X1, b2, out);
}

// Round 8
// 256.798 us; speedup vs baseline: 1.3161x; 1.0338x over previous
//
#include <hip/hip_runtime.h>
#include <hip/hip_bf16.h>
#include <stdint.h>

#define B_   2
#define S_   2048
#define D_   1024
#define H_   16
#define DH_  64
#define HID_ 4096
#define M_   4096  // B_*S_

typedef __bf16 bf16x8 __attribute__((ext_vector_type(8)));
typedef float  f32x4  __attribute__((ext_vector_type(4)));

typedef const uint32_t __attribute__((address_space(1))) u32g;
typedef uint32_t       __attribute__((address_space(3))) u32l;

__device__ __forceinline__ uint16_t f2bf(float f) {
  uint32_t u = __builtin_bit_cast(uint32_t, f);
  u += 0x7FFFu + ((u >> 16) & 1u);   // RNE
  return (uint16_t)(u >> 16);
}

__device__ __forceinline__ float bf2f(uint16_t u) {
  return __builtin_bit_cast(float, (uint32_t)u << 16);
}

__device__ __forceinline__ void gload_lds16(const void* g, void* l) {
  __builtin_amdgcn_global_load_lds((u32g*)g, (u32l*)l, 16, 0, 0);
}

// swizzled LDS 16B read: row-major [*][64] bf16 tile, byte ^= (row&7)<<4
__device__ __forceinline__ const bf16x8* lds8p(const uint16_t* base, int row,
                                               int cole) {
  int byt = (cole * 2) ^ ((row & 7) << 4);
  return reinterpret_cast<const bf16x8*>(base + row * 64 + (byt >> 1));
}

// ---------- weight convert + transpose: W (K,N) f32 -> WT (N,K) bf16 ----------
__global__ void wconv_t(const float* __restrict__ W, uint16_t* __restrict__ WT,
                        int K, int N) {
  __shared__ float tile[32][33];
  int n0 = blockIdx.x * 32, k0 = blockIdx.y * 32;
  int tx = threadIdx.x, ty = threadIdx.y;  // (32,8)
#pragma unroll
  for (int i = 0; i < 4; ++i)
    tile[ty + i * 8][tx] = W[(size_t)(k0 + ty + i * 8) * N + n0 + tx];
  __syncthreads();
#pragma unroll
  for (int i = 0; i < 4; ++i)
    WT[(size_t)(n0 + ty + i * 8) * K + k0 + tx] = f2bf(tile[tx][ty + i * 8]);
}

// ---------- layernorm: f32 row (1024) -> bf16 ----------
__global__ __launch_bounds__(256) void ln_k(const float* __restrict__ x,
                                            const float* __restrict__ sc,
                                            const float* __restrict__ sh,
                                            uint16_t* __restrict__ out) {
  int row = blockIdx.x;
  int t = threadIdx.x;
  float4 v = reinterpret_cast<const float4*>(x + (size_t)row * D_)[t];
  float s = v.x + v.y + v.z + v.w;
  float ss = v.x * v.x + v.y * v.y + v.z * v.z + v.w * v.w;
#pragma unroll
  for (int off = 32; off >= 1; off >>= 1) {
    s += __shfl_xor(s, off);
    ss += __shfl_xor(ss, off);
  }
  __shared__ float red[8];
  int wid = t >> 6, lane = t & 63;
  if (lane == 0) { red[wid] = s; red[wid + 4] = ss; }
  __syncthreads();
  s = red[0] + red[1] + red[2] + red[3];
  ss = red[4] + red[5] + red[6] + red[7];
  float mean = s * (1.0f / D_);
  float var = ss * (1.0f / D_) - mean * mean;
  float rstd = rsqrtf(var + 1e-5f);
  float4 g = reinterpret_cast<const float4*>(sc)[t];
  float4 b = reinterpret_cast<const float4*>(sh)[t];
  ushort4 o;
  o.x = f2bf(g.x * (v.x - mean) * rstd + b.x);
  o.y = f2bf(g.y * (v.y - mean) * rstd + b.y);
  o.z = f2bf(g.z * (v.z - mean) * rstd + b.z);
  o.w = f2bf(g.w * (v.w - mean) * rstd + b.w);
  reinterpret_cast<ushort4*>(out + (size_t)row * D_)[t] = o;
}

// ---------- out = resid + bias + sum of 4 bf16 partials (split-K reduce) ------
__global__ __launch_bounds__(256) void reduce4_k(
    const uint16_t* __restrict__ P0, const uint16_t* __restrict__ P1,
    const uint16_t* __restrict__ P2, const uint16_t* __restrict__ P3,
    const float* __restrict__ resid, const float* __restrict__ bias,
    float* __restrict__ out) {
  int row = blockIdx.x, t = threadIdx.x;
  size_t base = (size_t)row * D_ + t * 4;
  float4 r = *reinterpret_cast<const float4*>(resid + base);
  float4 b = reinterpret_cast<const float4*>(bias)[t];
  ushort4 u0 = *reinterpret_cast<const ushort4*>(P0 + base);
  ushort4 u1 = *reinterpret_cast<const ushort4*>(P1 + base);
  ushort4 u2 = *reinterpret_cast<const ushort4*>(P2 + base);
  ushort4 u3 = *reinterpret_cast<const ushort4*>(P3 + base);
  float4 o;
  o.x = r.x + b.x + bf2f(u0.x) + bf2f(u1.x) + bf2f(u2.x) + bf2f(u3.x);
  o.y = r.y + b.y + bf2f(u0.y) + bf2f(u1.y) + bf2f(u2.y) + bf2f(u3.y);
  o.z = r.z + b.z + bf2f(u0.z) + bf2f(u1.z) + bf2f(u2.z) + bf2f(u3.z);
  o.w = r.w + b.w + bf2f(u0.w) + bf2f(u1.w) + bf2f(u2.w) + bf2f(u3.w);
  *reinterpret_cast<float4*>(out + base) = o;
}

// ---------- transpose V (bh,s,dh) -> VT (bh,dh,s), bf16 ----------
__global__ void vtrans_k(const uint16_t* __restrict__ V, uint16_t* __restrict__ VT) {
  __shared__ uint16_t tile[32][33];
  int s0 = blockIdx.x * 32, d0 = blockIdx.y * 32, bh = blockIdx.z;
  int tx = threadIdx.x, ty = threadIdx.y;  // (32,8)
  const uint16_t* vb = V + (size_t)bh * S_ * DH_;
  uint16_t* vtb = VT + (size_t)bh * DH_ * S_;
#pragma unroll
  for (int i = 0; i < 4; ++i)
    tile[ty + i * 8][tx] = vb[(size_t)(s0 + ty + i * 8) * DH_ + d0 + tx];
  __syncthreads();
#pragma unroll
  for (int i = 0; i < 4; ++i)
    vtb[(size_t)(d0 + ty + i * 8) * S_ + s0 + tx] = tile[tx][ty + i * 8];
}

// ================== 256x256 8-phase GEMM (T2+T3+T4+T5), BK=64 ==================
// (unchanged from R7 — see R6 post-mortem: plain-store split-K partials)
template <int EPI>
__global__ __launch_bounds__(512, 2) void gemm8(
    const uint16_t* __restrict__ A, const uint16_t* __restrict__ BT,
    void* __restrict__ Cout, const float* __restrict__ bias,
    uint16_t* __restrict__ P0, uint16_t* __restrict__ P1,
    uint16_t* __restrict__ P2, uint16_t* __restrict__ P3,
    int M, int N, int K) {
  __shared__ uint16_t As[2][2][128 * 64];
  __shared__ uint16_t Bs[2][2][128 * 64];
  int t = threadIdx.x;
  int lane = t & 63, wid = t >> 6;
  int wm = wid >> 2, wn = wid & 3;
  int l15 = lane & 15, lk8 = (lane >> 4) * 8, lr4 = (lane >> 4) * 4;
  int gx = gridDim.x;
  int nwg = gx * gridDim.y;
  int bid = blockIdx.y * gx + blockIdx.x;
  int swz = (bid & 7) * (nwg >> 3) + (bid >> 3);
  int bx = swz % gx, by = swz / gx;
  int m0 = by * 256, n0 = bx * 256;
  int ksz = K / gridDim.z;
  int kbeg = blockIdx.z * ksz;
  int NT = ksz >> 6;

  int r0 = t >> 3, slot0 = t & 7;
  int scol = (slot0 ^ (r0 & 7)) * 8;  // pre-swizzled source col (involution)

  auto STAGE_A = [&](int kt, int half, int buf) {
    const uint16_t* src =
        A + (size_t)(m0 + half * 128 + r0) * K + kbeg + kt * 64 + scol;
    uint16_t* dst = &As[buf][half][t * 8];
    gload_lds16(src, dst);
    gload_lds16(src + (size_t)64 * K, dst + 4096);
  };
  auto STAGE_B = [&](int kt, int half, int buf) {
    const uint16_t* src =
        BT + (size_t)(n0 + half * 128 + r0) * K + kbeg + kt * 64 + scol;
    uint16_t* dst = &Bs[buf][half][t * 8];
    gload_lds16(src, dst);
    gload_lds16(src + (size_t)64 * K, dst + 4096);
  };

  bf16x8 a[4][2], b[2][2];
  auto LDA = [&](int buf, int mh) {
#pragma unroll
    for (int j = 0; j < 4; ++j)
#pragma unroll
      for (int kk = 0; kk < 2; ++kk)
        a[j][kk] = *lds8p(As[buf][mh], wm * 64 + j * 16 + l15, kk * 32 + lk8);
  };
  auto LDB = [&](int buf, int nh) {
#pragma unroll
    for (int jj = 0; jj < 2; ++jj)
#pragma unroll
      for (int kk = 0; kk < 2; ++kk)
        b[jj][kk] = *lds8p(Bs[buf][nh], wn * 32 + jj * 16 + l15, kk * 32 + lk8);
  };

  f32x4 acc[8][4] = {};
  auto MM = [&](int mh, int nh) {
    __builtin_amdgcn_s_setprio(1);
#pragma unroll
    for (int kk = 0; kk < 2; ++kk)
#pragma unroll
      for (int j = 0; j < 4; ++j)
#pragma unroll
        for (int jj = 0; jj < 2; ++jj)
          acc[mh * 4 + j][nh * 2 + jj] = __builtin_amdgcn_mfma_f32_16x16x32_bf16(
              a[j][kk], b[jj][kk], acc[mh * 4 + j][nh * 2 + jj], 0, 0, 0);
    __builtin_amdgcn_s_setprio(0);
  };
  auto BAR = [&]() {
    __builtin_amdgcn_s_barrier();
    asm volatile("" ::: "memory");
  };
  auto LGKM0 = [&]() {
    asm volatile("s_waitcnt lgkmcnt(0)" ::: "memory");
    __builtin_amdgcn_sched_barrier(0);
  };

  STAGE_A(0, 0, 0);
  STAGE_B(0, 1, 0);
  STAGE_B(0, 0, 0);
  STAGE_A(0, 1, 0);
  STAGE_A(1, 0, 1);
  STAGE_B(1, 1, 1);
  asm volatile("s_waitcnt vmcnt(4)" ::: "memory");
  BAR();

  for (int T = 0; T < NT; ++T) {
    int cur = T & 1;
    LDA(cur, 0);
    LDB(cur, 0);
    if (T + 1 < NT) STAGE_B(T + 1, 0, cur ^ 1);
    BAR(); LGKM0();
    MM(0, 0);
    BAR();
    LDB(cur, 1);
    if (T + 1 < NT) STAGE_A(T + 1, 1, cur ^ 1);
    BAR(); LGKM0();
    MM(0, 1);
    BAR();
    LDA(cur, 1);
    if (T + 2 < NT) STAGE_A(T + 2, 0, cur);
    BAR(); LGKM0();
    MM(1, 1);
    BAR();
    LDB(cur, 0);
    if (T + 2 < NT) STAGE_B(T + 2, 1, cur);
    BAR(); LGKM0();
    MM(1, 0);
    if (T + 1 < NT) {
      if (T == NT - 2) {
        asm volatile("s_waitcnt vmcnt(0)" ::: "memory");
      } else {
        asm volatile("s_waitcnt vmcnt(4)" ::: "memory");
      }
    }
    BAR();
  }

  uint16_t* Pz = nullptr;
  if constexpr (EPI == 3) {
    int z = blockIdx.z;
    Pz = (z == 0) ? P0 : (z == 1) ? P1 : (z == 2) ? P2 : P3;
  }
#pragma unroll
  for (int mi = 0; mi < 8; ++mi) {
#pragma unroll
    for (int ni = 0; ni < 4; ++ni) {
#pragma unroll
      for (int rr = 0; rr < 4; ++rr) {
        int gm = m0 + (mi >> 2) * 128 + wm * 64 + (mi & 3) * 16 + lr4 + rr;
        int gn = n0 + (ni >> 1) * 128 + wn * 32 + (ni & 1) * 16 + l15;
        float v = acc[mi][ni][rr];
        if constexpr (EPI == 0) {
          int which = gn >> 10, nc = gn & 1023;
          int h = nc >> 6, dh = nc & 63;
          int bb = gm >> 11, s = gm & 2047;
          ((uint16_t*)Cout)[((size_t)which * 32 + bb * 16 + h) * (S_ * 64) +
                            (size_t)s * 64 + dh] = f2bf(v);
        } else if constexpr (EPI == 2) {
          float u = v + bias[gn];
          float y = 0.7978845608028654f * (u + 0.044715f * u * u * u);
          float e = __expf(2.0f * y);
          float th = 1.0f - 2.0f / (e + 1.0f);  // tanh(y), inf-safe
          ((uint16_t*)Cout)[(size_t)gm * N + gn] = f2bf(0.5f * u * (1.0f + th));
        } else {
          Pz[(size_t)gm * N + gn] = f2bf(v);
        }
      }
    }
  }
}

// ---------- 128x128 2-phase GEMM (kept for Wo only; T1+T2, single-buffer) -----
template <int EPI>
__global__ __launch_bounds__(256) void gemm_bt(
    const uint16_t* __restrict__ A, const uint16_t* __restrict__ BT,
    void* __restrict__ Cout, const float* __restrict__ bias,
    const float* __restrict__ resid, int M, int N, int K) {
  __shared__ uint16_t Asm_[128 * 64];
  __shared__ uint16_t Bsm_[128 * 64];
  int t = threadIdx.x;
  int lane = t & 63, wid = t >> 6;
  int wr = wid >> 1, wc = wid & 1;
  int nwg = gridDim.x * gridDim.y;
  int bid = blockIdx.y * gridDim.x + blockIdx.x;
  int swz = (bid & 7) * (nwg >> 3) + (bid >> 3);
  int bx = swz % gridDim.x, by = swz / gridDim.x;
  int m0 = by * 128, n0 = bx * 128;
  int l15 = lane & 15, lk8 = (lane >> 4) * 8;
  f32x4 acc[4][4] = {};

  auto STAGE = [&](int k0) {
#pragma unroll
    for (int it = 0; it < 4; ++it) {
      int idx = it * 256 + t;
      int r = idx >> 3, slot = idx & 7;
      int c = (slot ^ (r & 7)) * 8;
      gload_lds16(A + (size_t)(m0 + r) * K + k0 + c, &Asm_[idx * 8]);
      gload_lds16(BT + (size_t)(n0 + r) * K + k0 + c, &Bsm_[idx * 8]);
    }
  };

  int niter = K >> 6;
  for (int ki = 0; ki < niter; ++ki) {
    __syncthreads();
    STAGE(ki * 64);
    __syncthreads();
#pragma unroll
    for (int kk = 0; kk < 2; ++kk) {
      bf16x8 a[4], b[4];
#pragma unroll
      for (int mi = 0; mi < 4; ++mi)
        a[mi] = *lds8p(Asm_, wr * 64 + mi * 16 + l15, kk * 32 + lk8);
#pragma unroll
      for (int ni = 0; ni < 4; ++ni)
        b[ni] = *lds8p(Bsm_, wc * 64 + ni * 16 + l15, kk * 32 + lk8);
#pragma unroll
      for (int mi = 0; mi < 4; ++mi)
#pragma unroll
        for (int ni = 0; ni < 4; ++ni)
          acc[mi][ni] = __builtin_amdgcn_mfma_f32_16x16x32_bf16(
              a[mi], b[ni], acc[mi][ni], 0, 0, 0);
    }
  }
  int lr4 = (lane >> 4) * 4;
#pragma unroll
  for (int mi = 0; mi < 4; ++mi) {
#pragma unroll
    for (int ni = 0; ni < 4; ++ni) {
#pragma unroll
      for (int r = 0; r < 4; ++r) {
        int gm = m0 + wr * 64 + mi * 16 + lr4 + r;
        int gn = n0 + wc * 64 + ni * 16 + l15;
        float v = acc[mi][ni][r];
        if constexpr (EPI == 1) {
          ((float*)Cout)[(size_t)gm * N + gn] =
              resid[(size_t)gm * N + gn] + v + bias[gn];
        }
      }
    }
  }
}

// ---------- flash causal attention, QBLK=64 (4 waves x 16 rows), KVBLK=64 ----------
// R7 softmax surgery (VALU/stall-bound: VALUBusy 41.6%, MfmaUtil 8.7%):
//  - exp2 domain, scale folded to 0.125*log2(e); __builtin_amdgcn_exp2f = v_exp_f32
//  - lsum kept as per-lane partial (fac is row-uniform) -> ONE shuffle-reduce per
//    q-tile instead of per K-tile (removes a 4-stage dependent shfl chain/iter)
//  - defer-max (T13, THR=8): skip fac + o-rescale when __all(pmax <= m+8);
//    P bounded by 2^8, bf16/f32 accum safe
#define SCL_ 0.18033688011112042f  // 0.125 * log2(e)

__global__ __launch_bounds__(256) void attn_k(const uint16_t* __restrict__ Q,
                                              const uint16_t* __restrict__ Kv,
                                              const uint16_t* __restrict__ VT,
                                              uint16_t* __restrict__ ctx) {
  __shared__ uint16_t Ksm[2][64 * 64];
  __shared__ uint16_t Vsm[2][64 * 64];  // Vt tile: [dh][key]
  __shared__ uint16_t Psm[4][16 * 64];
  int bh = blockIdx.y;
  int t = threadIdx.x, lane = t & 63, wid = t >> 6;
  int l15 = lane & 15, lk8 = (lane >> 4) * 8, lr4 = (lane >> 4) * 4;

  auto STAGE = [&](int kt, int bufi) {
    int k0 = kt * 64;
#pragma unroll
    for (int it = 0; it < 2; ++it) {
      int idx = it * 256 + t;
      int r = idx >> 3, slot = idx & 7;
      int c = (slot ^ (r & 7)) * 8;
      gload_lds16(Kv + ((size_t)bh * S_ + k0 + r) * 64 + c, &Ksm[bufi][idx * 8]);
      gload_lds16(VT + ((size_t)bh * 64 + r) * S_ + k0 + c, &Vsm[bufi][idx * 8]);
    }
  };

  for (int half = 0; half < 2; ++half) {
    int qt = half ? 31 - blockIdx.x : blockIdx.x;
    int q0 = qt * 64;
    bf16x8 qf[2];
#pragma unroll
    for (int kk = 0; kk < 2; ++kk)
      qf[kk] = *reinterpret_cast<const bf16x8*>(
          &Q[((size_t)bh * S_ + q0 + wid * 16 + l15) * 64 + kk * 32 + lk8]);
    f32x4 o[4] = {};
    float mrow[4], lsum[4];
#pragma unroll
    for (int r = 0; r < 4; ++r) { mrow[r] = -3.0e38f; lsum[r] = 0.0f; }

    int nkt = qt + 1;
    STAGE(0, 0);
    for (int kt = 0; kt < nkt; ++kt) {
      int cur = kt & 1;
      if (kt + 1 < nkt) {
        STAGE(kt + 1, cur ^ 1);
        asm volatile("s_waitcnt vmcnt(4)" ::: "memory");
      } else {
        asm volatile("s_waitcnt vmcnt(0)" ::: "memory");
      }
      __builtin_amdgcn_s_barrier();
      asm volatile("" ::: "memory");
      __builtin_amdgcn_sched_barrier(0);
      const uint16_t* Kb = Ksm[cur];
      const uint16_t* Vb = Vsm[cur];

      f32x4 sf[4] = {};
#pragma unroll
      for (int kk = 0; kk < 2; ++kk)
#pragma unroll
        for (int nt = 0; nt < 4; ++nt) {
          bf16x8 kb = *lds8p(Kb, nt * 16 + l15, kk * 32 + lk8);
          sf[nt] = __builtin_amdgcn_mfma_f32_16x16x32_bf16(qf[kk], kb, sf[nt], 0, 0, 0);
        }
      float sv[4][4];
      if (kt == qt) {  // diagonal tile: causal mask (wave-uniform branch)
#pragma unroll
        for (int nt = 0; nt < 4; ++nt)
#pragma unroll
          for (int r = 0; r < 4; ++r) {
            float s = sf[nt][r] * SCL_;
            int key = nt * 16 + l15;
            int qr = wid * 16 + lr4 + r;
            sv[nt][r] = (key <= qr) ? s : -3.0e38f;
          }
      } else {
#pragma unroll
        for (int nt = 0; nt < 4; ++nt)
#pragma unroll
          for (int r = 0; r < 4; ++r) sv[nt][r] = sf[nt][r] * SCL_;
      }
      float pmax[4];
#pragma unroll
      for (int r = 0; r < 4; ++r)
        pmax[r] = fmaxf(fmaxf(sv[0][r], sv[1][r]), fmaxf(sv[2][r], sv[3][r]));
#pragma unroll
      for (int off = 8; off >= 1; off >>= 1)
#pragma unroll
        for (int r = 0; r < 4; ++r)
          pmax[r] = fmaxf(pmax[r], __shfl_xor(pmax[r], off));
      // defer-max: only rescale when some row's max grew past THR=8 (exp2 dom)
      bool grow = (pmax[0] > mrow[0] + 8.0f) | (pmax[1] > mrow[1] + 8.0f) |
                  (pmax[2] > mrow[2] + 8.0f) | (pmax[3] > mrow[3] + 8.0f);
      if (__any(grow)) {
        float fac[4];
#pragma unroll
        for (int r = 0; r < 4; ++r) {
          float mn = fmaxf(mrow[r], pmax[r]);
          fac[r] = __builtin_amdgcn_exp2f(mrow[r] - mn);
          mrow[r] = mn;
          lsum[r] *= fac[r];
        }
#pragma unroll
        for (int dt = 0; dt < 4; ++dt)
#pragma unroll
          for (int r = 0; r < 4; ++r) o[dt][r] *= fac[r];
      }
      // P = exp2(sv - m); lsum stays a per-lane partial (reduced once at end)
#pragma unroll
      for (int nt = 0; nt < 4; ++nt)
#pragma unroll
        for (int r = 0; r < 4; ++r) {
          float p = __builtin_amdgcn_exp2f(sv[nt][r] - mrow[r]);
          lsum[r] += p;
          int prow = lr4 + r, pcol = nt * 16 + l15;
          Psm[wid][prow * 64 + ((((pcol * 2) ^ ((prow & 7) << 4))) >> 1)] = f2bf(p);
        }
      // PV: ctx += P (16q x 64k) @ Vt^T (64k x 64dh)
#pragma unroll
      for (int kk = 0; kk < 2; ++kk) {
        bf16x8 pa = *lds8p(Psm[wid], l15, kk * 32 + lk8);
#pragma unroll
        for (int dt = 0; dt < 4; ++dt) {
          bf16x8 vb = *lds8p(Vb, dt * 16 + l15, kk * 32 + lk8);
          o[dt] = __builtin_amdgcn_mfma_f32_16x16x32_bf16(pa, vb, o[dt], 0, 0, 0);
        }
      }
      asm volatile("s_waitcnt lgkmcnt(0)" ::: "memory");
      __builtin_amdgcn_sched_barrier(0);
      __builtin_amdgcn_s_barrier();
      asm volatile("" ::: "memory");
    }
    // final lsum reduce (once per q-tile; fac was row-uniform so partials OK)
#pragma unroll
    for (int off = 8; off >= 1; off >>= 1)
#pragma unroll
      for (int r = 0; r < 4; ++r) lsum[r] += __shfl_xor(lsum[r], off);
    int b = bh >> 4, h = bh & 15;
#pragma unroll
    for (int dt = 0; dt < 4; ++dt)
#pragma unroll
      for (int r = 0; r < 4; ++r) {
        int s = q0 + wid * 16 + lr4 + r;
        int dh = dt * 16 + l15;
        ctx[((size_t)(b * S_ + s)) * D_ + h * 64 + dh] = f2bf(o[dt][r] / lsum[r]);
      }
  }
}

extern "C" void kernel_launch(void* const* d_in, const int* in_sizes, int n_in,
                              void* d_out, int out_size, void* d_ws, size_t ws_size,
                              hipStream_t stream) {
  const float* x    = (const float*)d_in[0];
  const float* Wq   = (const float*)d_in[1];
  const float* Wk   = (const float*)d_in[2];
  const float* Wv   = (const float*)d_in[3];
  const float* Wo   = (const float*)d_in[4];
  const float* bo   = (const float*)d_in[5];
  const float* W1   = (const float*)d_in[6];
  const float* b1   = (const float*)d_in[7];
  const float* W2   = (const float*)d_in[8];
  const float* b2   = (const float*)d_in[9];
  const float* ln1s = (const float*)d_in[10];
  const float* ln1b = (const float*)d_in[11];
  const float* ln2s = (const float*)d_in[12];
  const float* ln2b = (const float*)d_in[13];
  float* out = (float*)d_out;
  char* ws = (char*)d_ws;

  const size_t MB = 1024 * 1024;
  uint16_t* WQKVT = (uint16_t*)(ws + 0);        // 6 MB  (3072 x 1024)
  uint16_t* WOT   = (uint16_t*)(ws + 6 * MB);   // 2 MB  (1024 x 1024)
  uint16_t* W1T   = (uint16_t*)(ws + 8 * MB);   // 8 MB  (4096 x 1024)
  uint16_t* W2T   = (uint16_t*)(ws + 16 * MB);  // 8 MB  (1024 x 4096)
  uint16_t* H1    = (uint16_t*)(ws + 24 * MB);  // 8 MB  (LN1 out; reused for LN2 out)
  float*    X1    = (float*)(ws + 32 * MB);     // 16 MB (attn residual, f32)
  uint16_t* QKV   = (uint16_t*)(ws + 48 * MB);  // 24 MB (q,k,v in (bh,s,dh))
  uint16_t* VTb   = (uint16_t*)(ws + 72 * MB);  // 8 MB  (v transposed (bh,dh,s))
  uint16_t* CTX   = (uint16_t*)(ws + 80 * MB);  // 8 MB
  uint16_t* FFH   = (uint16_t*)(ws + 48 * MB);  // 32 MB (reuses dead QKV/VT, 48-80)
  // split-K bf16 partials (8 MB each), placed in regions dead by FFN2 time:
  uint16_t* SP0   = (uint16_t*)(ws + 0);        // over WQKVT+WOT (dead after Wo)
  uint16_t* SP1   = (uint16_t*)(ws + 8 * MB);   // over W1T (dead after FFN1)
  uint16_t* SP2   = (uint16_t*)(ws + 24 * MB);  // over H1 (dead after FFN1)
  uint16_t* SP3   = (uint16_t*)(ws + 80 * MB);  // over CTX (dead after Wo)

  dim3 b32x8(32, 8);
  wconv_t<<<dim3(32, 32), b32x8, 0, stream>>>(Wq, WQKVT, 1024, 1024);
  wconv_t<<<dim3(32, 32), b32x8, 0, stream>>>(Wk, WQKVT + 1024 * 1024, 1024, 1024);
  wconv_t<<<dim3(32, 32), b32x8, 0, stream>>>(Wv, WQKVT + 2 * 1024 * 1024, 1024, 1024);
  wconv_t<<<dim3(32, 32), b32x8, 0, stream>>>(Wo, WOT, 1024, 1024);
  wconv_t<<<dim3(128, 32), b32x8, 0, stream>>>(W1, W1T, 1024, 4096);
  wconv_t<<<dim3(32, 128), b32x8, 0, stream>>>(W2, W2T, 4096, 1024);

  // LN1 -> h (bf16)
  ln_k<<<M_, 256, 0, stream>>>(x, ln1s, ln1b, H1);
  // QKV projections (fused N=3072), 256^2 8-phase, head-split epilogue
  gemm8<0><<<dim3(12, 16), 512, 0, stream>>>(H1, WQKVT, QKV, nullptr,
                                             nullptr, nullptr, nullptr, nullptr,
                                             M_, 3072, 1024);
  const uint16_t* Qp = QKV;
  const uint16_t* Kp = QKV + (size_t)32 * S_ * 64;
  const uint16_t* Vp = QKV + (size_t)64 * S_ * 64;
  vtrans_k<<<dim3(64, 2, 32), b32x8, 0, stream>>>(Vp, VTb);
  // flash causal attention (paired q-tiles)
  attn_k<<<dim3(16, 32), 256, 0, stream>>>(Qp, Kp, VTb, CTX);
  // Wo projection + bias + residual -> X1 (f32), 128^2 path
  gemm_bt<1><<<dim3(8, 32), 256, 0, stream>>>(CTX, WOT, X1, bo, x, M_, 1024, 1024);
  // LN2 -> h2 (bf16, reuse H1)
  ln_k<<<M_, 256, 0, stream>>>(X1, ln2s, ln2b, H1);
  // FFN1 + GELU -> FFH (bf16), 256^2 8-phase
  gemm8<2><<<dim3(16, 16), 512, 0, stream>>>(H1, W1T, FFH, b1,
                                             nullptr, nullptr, nullptr, nullptr,
                                             M_, 4096, 1024);
  // FFN2 split-K=4, 256^2 8-phase: bf16 partials (plain stores, no atomics)
  gemm8<3><<<dim3(4, 16, 4), 512, 0, stream>>>(FFH, W2T, nullptr, nullptr,
                                               SP0, SP1, SP2, SP3,
                                               M_, 1024, 4096);
  // out = X1 + b2 + sum(partials)
  reduce4_k<<<M_, 256, 0, stream>>>(SP0, SP1, SP2, SP3, X1, b2, out);
}